// Round 8
// baseline (5894.666 us; speedup 1.0000x reference)
//
#include <hip/hip_runtime.h>
#include <hip/hip_bf16.h>

// ---------------------------------------------------------------------------
// TransformerDecoderBlock (MLA-style) for MI355X / gfx950
// B=2 S=2048 D=2048 NH=16 DH=128 LAT=512
// ---------------------------------------------------------------------------

#define DEVI __device__ __forceinline__

typedef __attribute__((ext_vector_type(8))) short bf16x8;
typedef __attribute__((ext_vector_type(4))) float f32x4;
typedef __attribute__((ext_vector_type(16))) float f32x16;

DEVI unsigned short f2bf(float f) {
  union { float f; unsigned u; } v; v.f = f;
  unsigned r = v.u + 0x7fffu + ((v.u >> 16) & 1u);
  return (unsigned short)(r >> 16);
}

DEVI float bf2f(unsigned short u) {
  union { unsigned u; float f; } v; v.u = ((unsigned)u) << 16;
  return v.f;
}

#define GLDS16(gp, lp)                                              \
  __builtin_amdgcn_global_load_lds(                                 \
      (__attribute__((address_space(1))) void*)(gp),                \
      (__attribute__((address_space(3))) void*)(lp), 16, 0, 0)

#define NEG_INF (-__builtin_inff())

// ---------------------------------------------------------------------------
// cast fp32 -> bf16 (n multiple of 4)
// ---------------------------------------------------------------------------
__global__ __launch_bounds__(256) void cast_f32_bf16(
    const float* __restrict__ in, unsigned short* __restrict__ out, long n) {
  long i = ((long)blockIdx.x * 256 + threadIdx.x) * 4;
  if (i >= n) return;
  const float4 v = *reinterpret_cast<const float4*>(in + i);
  ushort4 o;
  o.x = f2bf(v.x); o.y = f2bf(v.y); o.z = f2bf(v.z); o.w = f2bf(v.w);
  *reinterpret_cast<ushort4*>(out + i) = o;
}

// ---------------------------------------------------------------------------
// transpose + cast: in (R x C) f32  ->  out (C x R) bf16.  R,C multiples of 32
// ---------------------------------------------------------------------------
__global__ __launch_bounds__(256) void transpose_cast(
    const float* __restrict__ in, unsigned short* __restrict__ out, int R, int C) {
  __shared__ float tile[32][33];
  const int c0 = blockIdx.x * 32, r0 = blockIdx.y * 32;
  const int tx = threadIdx.x & 31, ty = threadIdx.x >> 5;  // ty 0..7
#pragma unroll
  for (int i = 0; i < 32; i += 8)
    tile[ty + i][tx] = in[(long)(r0 + ty + i) * C + c0 + tx];
  __syncthreads();
#pragma unroll
  for (int i = 0; i < 32; i += 8)
    out[(long)(c0 + ty + i) * R + r0 + tx] = f2bf(tile[tx][ty + i]);
}

// ---------------------------------------------------------------------------
// V transpose: KV (B*S x 4096 bf16, V at cols [2048,4096)) ->
//   Vt[bh][d][s]  (32 x 128 x 2048 bf16)
// ---------------------------------------------------------------------------
__global__ __launch_bounds__(256) void v_transpose(
    const unsigned short* __restrict__ KV, unsigned short* __restrict__ Vt) {
  __shared__ unsigned short sh[32][33];
  const int s0 = blockIdx.x * 32, d0 = blockIdx.y * 32, bh = blockIdx.z;
  const int b = bh >> 4, h = bh & 15;
  const int tx = threadIdx.x & 31, ty = threadIdx.x >> 5;  // ty 0..7
#pragma unroll
  for (int i = 0; i < 32; i += 8)
    sh[ty + i][tx] = KV[((long)(b * 2048 + s0 + ty + i)) * 4096 + 2048 + h * 128 + d0 + tx];
  __syncthreads();
#pragma unroll
  for (int i = 0; i < 32; i += 8)
    Vt[((long)(bh * 128 + d0 + ty + i)) * 2048 + s0 + tx] = sh[tx][ty + i];
}

// ---------------------------------------------------------------------------
// block reduce (256 threads = 4 waves)
// ---------------------------------------------------------------------------
DEVI float blockReduceSum(float v) {
  v += __shfl_xor(v, 1);  v += __shfl_xor(v, 2);  v += __shfl_xor(v, 4);
  v += __shfl_xor(v, 8);  v += __shfl_xor(v, 16); v += __shfl_xor(v, 32);
  __shared__ float red[4];
  if ((threadIdx.x & 63) == 0) red[threadIdx.x >> 6] = v;
  __syncthreads();
  v = red[0] + red[1] + red[2] + red[3];
  __syncthreads();
  return v;
}

// ---------------------------------------------------------------------------
// LayerNorm over W cols, one block (256 thr) per row; input row stride ldin.
// f32 in -> bf16 out (out contiguous, stride W)
// ---------------------------------------------------------------------------
template <int W>
__global__ __launch_bounds__(256) void layernorm_bf16(
    const float* __restrict__ in, const float* __restrict__ g,
    const float* __restrict__ b, unsigned short* __restrict__ out, int ldin) {
  constexpr int VPT = W / 256;
  const long row = blockIdx.x;
  const float* x = in + row * ldin;
  float v[VPT];
  float s = 0.f;
#pragma unroll
  for (int i = 0; i < VPT; i++) { v[i] = x[threadIdx.x + i * 256]; s += v[i]; }
  s = blockReduceSum(s);
  const float mean = s * (1.0f / W);
  float s2 = 0.f;
#pragma unroll
  for (int i = 0; i < VPT; i++) { float d = v[i] - mean; s2 += d * d; }
  s2 = blockReduceSum(s2);
  const float rstd = rsqrtf(s2 * (1.0f / W) + 1e-5f);
#pragma unroll
  for (int i = 0; i < VPT; i++) {
    const int c = threadIdx.x + i * 256;
    out[row * W + c] = f2bf((v[i] - mean) * rstd * g[c] + b[c]);
  }
}

// ---------------------------------------------------------------------------
// combine_ln: fused W_o-combine + residual + LayerNorm (W=2048).
//   x2 = x + p0 + p1 ; h1 = LN(x2) * g + b
// ---------------------------------------------------------------------------
__global__ __launch_bounds__(256) void combine_ln(
    const unsigned short* __restrict__ p, const float* __restrict__ xres,
    const float* __restrict__ g, const float* __restrict__ b,
    float* __restrict__ x2, unsigned short* __restrict__ h1, long n) {
  const int c0 = threadIdx.x * 8;
  const long base = (long)blockIdx.x * 2048 + c0;
  float v[8];
  float s = 0.f;
#pragma unroll
  for (int hh = 0; hh < 2; hh++) {
    const long i = base + hh * 4;
    const ushort4 a  = *reinterpret_cast<const ushort4*>(p + i);
    const ushort4 bb = *reinterpret_cast<const ushort4*>(p + n + i);
    const float4 r = *reinterpret_cast<const float4*>(xres + i);
    float4 o;
    o.x = r.x + bf2f(a.x) + bf2f(bb.x);
    o.y = r.y + bf2f(a.y) + bf2f(bb.y);
    o.z = r.z + bf2f(a.z) + bf2f(bb.z);
    o.w = r.w + bf2f(a.w) + bf2f(bb.w);
    *reinterpret_cast<float4*>(x2 + i) = o;
    v[hh * 4 + 0] = o.x; v[hh * 4 + 1] = o.y;
    v[hh * 4 + 2] = o.z; v[hh * 4 + 3] = o.w;
    s += o.x + o.y + o.z + o.w;
  }
  s = blockReduceSum(s);
  const float mean = s * (1.0f / 2048.f);
  float s2 = 0.f;
#pragma unroll
  for (int i = 0; i < 8; i++) { float d = v[i] - mean; s2 += d * d; }
  s2 = blockReduceSum(s2);
  const float rstd = rsqrtf(s2 * (1.0f / 2048.f) + 1e-5f);
#pragma unroll
  for (int hh = 0; hh < 2; hh++) {
    const float4 gv = *reinterpret_cast<const float4*>(g + c0 + hh * 4);
    const float4 bv = *reinterpret_cast<const float4*>(b + c0 + hh * 4);
    ushort4 o;
    o.x = f2bf((v[hh * 4 + 0] - mean) * rstd * gv.x + bv.x);
    o.y = f2bf((v[hh * 4 + 1] - mean) * rstd * gv.y + bv.y);
    o.z = f2bf((v[hh * 4 + 2] - mean) * rstd * gv.z + bv.z);
    o.w = f2bf((v[hh * 4 + 3] - mean) * rstd * gv.w + bv.w);
    *reinterpret_cast<ushort4*>(h1 + base + hh * 4) = o;
  }
}

// ---------------------------------------------------------------------------
// gemm_bt: C(MxN) = A * Bt^T, 128x128 tile, BK=32, 4 waves (for small-N
// GEMMs: merged dq|dkv, Q-up).
// ---------------------------------------------------------------------------
template <bool BIAS, bool RELU, bool RES, bool OBF16>
__global__ __launch_bounds__(256) void gemm_bt(
    const unsigned short* __restrict__ A, const unsigned short* __restrict__ Bt,
    const float* __restrict__ bias, const float* __restrict__ res,
    void* __restrict__ Cout, int M, int N, int K) {
  __shared__ __align__(16) unsigned short As[2][128 * 32];
  __shared__ __align__(16) unsigned short Bs[2][128 * 32];

  const int m0 = blockIdx.x * 128;
  const int n0 = blockIdx.y * 128;
  const int tid = threadIdx.x;
  const int lane = tid & 63, w = tid >> 6;
  const int wr = (w >> 1) * 64, wc = (w & 1) * 64;
  const int lrow = lane & 15, lk = (lane >> 4) * 8;

  f32x4 acc[4][4] = {};

  const int nt = K >> 5;
  const int r_ = (tid * 8) >> 5;      // 0..63
  const int c_ = (tid * 8) & 31;

#define STAGE(buf, t)                                                        \
  {                                                                          \
    const long k0 = (long)(t) * 32;                                          \
    GLDS16(A + (long)(m0 + r_) * K + k0 + c_, &As[buf][tid * 8]);            \
    GLDS16(A + (long)(m0 + 64 + r_) * K + k0 + c_, &As[buf][2048 + tid * 8]);\
    GLDS16(Bt + (long)(n0 + r_) * K + k0 + c_, &Bs[buf][tid * 8]);           \
    GLDS16(Bt + (long)(n0 + 64 + r_) * K + k0 + c_, &Bs[buf][2048 + tid * 8]);\
  }

  STAGE(0, 0)
  __syncthreads();
  int cur = 0;
  for (int t = 0; t < nt; t++) {
    if (t + 1 < nt) STAGE(cur ^ 1, t + 1)
    bf16x8 fa[4], fb[4];
#pragma unroll
    for (int i = 0; i < 4; i++) {
      fa[i] = *reinterpret_cast<const bf16x8*>(&As[cur][(wr + i * 16 + lrow) * 32 + lk]);
      fb[i] = *reinterpret_cast<const bf16x8*>(&Bs[cur][(wc + i * 16 + lrow) * 32 + lk]);
    }
#pragma unroll
    for (int i = 0; i < 4; i++)
#pragma unroll
      for (int j = 0; j < 4; j++)
        acc[i][j] = __builtin_amdgcn_mfma_f32_16x16x32_bf16(fa[i], fb[j], acc[i][j], 0, 0, 0);
    __syncthreads();
    cur ^= 1;
  }
#undef STAGE

#pragma unroll
  for (int i = 0; i < 4; i++) {
#pragma unroll
    for (int j = 0; j < 4; j++) {
      const int row = m0 + wr + i * 16 + ((lane >> 4) << 2);
      const int col = n0 + wc + j * 16 + lrow;
      float bv = 0.f;
      if (BIAS) bv = bias[col];
#pragma unroll
      for (int r = 0; r < 4; r++) {
        float v = acc[i][j][r];
        const long idx = (long)(row + r) * N + col;
        if (BIAS) v += bv;
        if (RELU) v = fmaxf(v, 0.f);
        if (RES) v += res[idx];
        if (OBF16) ((unsigned short*)Cout)[idx] = f2bf(v);
        else       ((float*)Cout)[idx] = v;
      }
    }
  }
}

// ---------------------------------------------------------------------------
// gemm256p: software-pipelined 256x256 GEMM, BK=64, 8 waves, 32x32x16 MFMA.
// Waves 2x4: wave owns 128 rows x 64 cols (4x2 tiles of 32x32).
// KEY STRUCTURE (m201 discipline): each region issues the ds_reads for the
// NEXT phase, then runs the MFMA of the CURRENT phase -> DS pipe fills the
// X/Y fragment double-buffer while the MFMA pipe crunches; compiler inserts
// partial lgkmcnt waits only where the true dependency is.
//   region A(t): reads(t,1)->Y | stage h1(t+1) | MFMA(X=(t,0)) | vmcnt(4) bar
//   region B(t): reads(t+1,0)->X | stage h0(t+2) | MFMA(Y=(t,1)) | vmcnt(4) bar
// vmcnt ledger (4 loads/stage-half, FIFO): end A(t) outstanding
// {h0(t+1),h1(t+1)} -> vmcnt(4) drains h0(t+1) (read next region); end B(t)
// outstanding {h1(t+1),h0(t+2)} -> vmcnt(4) drains h1(t+1). Tail: vmcnt(0).
// WAR-safety: pending reads and STG writes always differ in (buf,kh).
// Swizzle: k-octet ko of row rr lives in slot ko ^ f(rr),
// f(rr)=((rr>>1)&1)<<1 | ((rr>>2)&1) — bank-group-complete for BOTH the
// 8-consecutive-lane and the (l,l+32)-paired LDS batch models (R7's
// conflicts came from khi=lane>>5 colliding under the pair model).
// Frag layouts (m74/m101): A/B row|col=lane&31, k-octet=lane>>5;
// C/D col=lane&31, row=(reg&3)+8*(reg>>2)+4*(lane>>5).
// blockIdx.z = split-K slice: A/Bt advanced by z*kOff, C by z*M*N.
// ---------------------------------------------------------------------------
template <bool BIAS, bool RELU, bool OBF16>
__global__ __launch_bounds__(512, 1) void gemm256p(
    const unsigned short* __restrict__ A, const unsigned short* __restrict__ Bt,
    const float* __restrict__ bias, void* __restrict__ Cout,
    int M, int N, int lda, int ldb, int kLen, long kOff) {
  __shared__ __align__(16) unsigned short L[2][2][2][256 * 32];

  const int m0 = blockIdx.x * 256, n0 = blockIdx.y * 256;
  const long ka = (long)blockIdx.z * kOff;
  const int tid = threadIdx.x;
  const int lane = tid & 63, w = tid >> 6;
  const int wm = w >> 2, wn = w & 3;            // 2x4 waves: 128x64 each
  const int l31 = lane & 31, khi = lane >> 5;   // frag row/col, k-octet
  const int r_ = tid >> 2, s_ = tid & 3;        // staging row/slot

  f32x16 acc[4][2] = {};
  const int nt = kLen >> 6;

#define FSWZ(rr) ((((rr) >> 1) & 1) * 2 + (((rr) >> 2) & 1))

#define STG1(bb, ab, h, kh, t, P, base0, ld)                                   \
  {                                                                            \
    const long k0 = ka + (long)(t) * 64 + (kh) * 32;                           \
    const int rr = (h) * 128 + r_;                                             \
    GLDS16((P) + (long)((base0) + rr) * (ld) + k0 + ((s_ ^ FSWZ(rr)) << 3),    \
           &L[bb][ab][kh][((h) * 512 + tid) * 8]);                             \
  }
// stage A-half + B-half kh of tile t into buf bb (4 loads/thread)
#define STG_H(bb, kh, t)                                                       \
  STG1(bb, 0, 0, kh, t, A, m0, lda) STG1(bb, 0, 1, kh, t, A, m0, lda)          \
  STG1(bb, 1, 0, kh, t, Bt, n0, ldb) STG1(bb, 1, 1, kh, t, Bt, n0, ldb)

#define RD_FRAGS(fa, fb, bb, kh)                                               \
  _Pragma("unroll")                                                            \
  for (int i = 0; i < 4; i++) {                                                \
    const int rr = wm * 128 + i * 32 + l31;                                    \
    const int sw = FSWZ(rr);                                                   \
    _Pragma("unroll")                                                          \
    for (int ks = 0; ks < 2; ks++)                                             \
      fa[i][ks] = *reinterpret_cast<const bf16x8*>(                            \
          &L[bb][0][kh][(rr * 4 + ((ks * 2 + khi) ^ sw)) * 8]);                \
  }                                                                            \
  _Pragma("unroll")                                                            \
  for (int j = 0; j < 2; j++) {                                                \
    const int rc = wn * 64 + j * 32 + l31;                                     \
    const int sw = FSWZ(rc);                                                   \
    _Pragma("unroll")                                                          \
    for (int ks = 0; ks < 2; ks++)                                             \
      fb[j][ks] = *reinterpret_cast<const bf16x8*>(                            \
          &L[bb][1][kh][(rc * 4 + ((ks * 2 + khi) ^ sw)) * 8]);                \
  }

#define MFMA16(fa, fb)                                                         \
  __builtin_amdgcn_s_setprio(1);                                               \
  _Pragma("unroll")                                                            \
  for (int ks = 0; ks < 2; ks++)                                               \
    _Pragma("unroll")                                                          \
    for (int i = 0; i < 4; i++)                                                \
      _Pragma("unroll")                                                        \
      for (int j = 0; j < 2; j++)                                              \
        acc[i][j] = __builtin_amdgcn_mfma_f32_32x32x16_bf16(                   \
            fa[i][ks], fb[j][ks], acc[i][j], 0, 0, 0);                         \
  __builtin_amdgcn_s_setprio(0);

  bf16x8 faX[4][2], fbX[2][2], faY[4][2], fbY[2][2];

  // prologue: tile 0 (both halves) -> buf 0; drain; preload X=(0,0); stage h0(1)
  STG_H(0, 0, 0) STG_H(0, 1, 0)
  asm volatile("s_waitcnt vmcnt(0)\n\ts_barrier" ::: "memory");
  RD_FRAGS(faX, fbX, 0, 0)
  if (nt > 1) STG_H(1, 0, 1)

  for (int t = 0; t < nt; t++) {
    const int bu = t & 1, bn = bu ^ 1;
    const bool more = (t + 1 < nt);
    // region A: reads (t,1)->Y ; stage h1(t+1) ; MFMA X=(t,0)
    RD_FRAGS(faY, fbY, bu, 1)
    if (more) {
      STG_H(bn, 1, t + 1)
      MFMA16(faX, fbX)
      asm volatile("s_waitcnt vmcnt(4)\n\ts_barrier" ::: "memory");
      // region B: reads (t+1,0)->X ; stage h0(t+2) ; MFMA Y=(t,1)
      RD_FRAGS(faX, fbX, bn, 0)
      if (t + 2 < nt) {
        STG_H(bu, 0, t + 2)
        MFMA16(faY, fbY)
        asm volatile("s_waitcnt vmcnt(4)\n\ts_barrier" ::: "memory");
      } else {
        MFMA16(faY, fbY)
        asm volatile("s_waitcnt vmcnt(0)\n\ts_barrier" ::: "memory");
      }
    } else {
      MFMA16(faX, fbX)
      MFMA16(faY, fbY)
    }
  }
#undef STG1
#undef STG_H
#undef RD_FRAGS
#undef MFMA16
#undef FSWZ

  const long zoff = (long)blockIdx.z * (long)M * (long)N;
#pragma unroll
  for (int i = 0; i < 4; i++) {
#pragma unroll
    for (int j = 0; j < 2; j++) {
      const int col = n0 + wn * 64 + j * 32 + l31;
      float bv = 0.f;
      if (BIAS) bv = bias[col];
#pragma unroll
      for (int reg = 0; reg < 16; reg++) {
        const int row = m0 + wm * 128 + i * 32 + (reg & 3) + 8 * (reg >> 2) + 4 * khi;
        float v = acc[i][j][reg];
        if (BIAS) v += bv;
        if (RELU) v = fmaxf(v, 0.f);
        const long idx = zoff + (long)row * N + col;
        if (OBF16) ((unsigned short*)Cout)[idx] = f2bf(v);
        else       ((float*)Cout)[idx] = v;
      }
    }
  }
}

// ---------------------------------------------------------------------------
// combine split-K partials: out = p0 + p1 [+ bias[col]] + res  (f32)
// N = 2048 fixed (bias index = i & 2047), n = M*N, 4 elements/thread
// ---------------------------------------------------------------------------
template <bool BIAS>
__global__ __launch_bounds__(256) void combine2(
    const unsigned short* __restrict__ p, const float* __restrict__ bias,
    const float* __restrict__ res, float* __restrict__ out, long n) {
  const long i = ((long)blockIdx.x * 256 + threadIdx.x) * 4;
  if (i >= n) return;
  const ushort4 a = *reinterpret_cast<const ushort4*>(p + i);
  const ushort4 b = *reinterpret_cast<const ushort4*>(p + n + i);
  const float4 r = *reinterpret_cast<const float4*>(res + i);
  float4 o;
  o.x = bf2f(a.x) + bf2f(b.x) + r.x;
  o.y = bf2f(a.y) + bf2f(b.y) + r.y;
  o.z = bf2f(a.z) + bf2f(b.z) + r.z;
  o.w = bf2f(a.w) + bf2f(b.w) + r.w;
  if (BIAS) {
    const int col = (int)(i & 2047);
    const float4 bv = *reinterpret_cast<const float4*>(bias + col);
    o.x += bv.x; o.y += bv.y; o.z += bv.z; o.w += bv.w;
  }
  *reinterpret_cast<float4*>(out + i) = o;
}

// ---------------------------------------------------------------------------
// Causal flash attention, KVBLK=64, global_load_lds + XOR-swizzled tiles.
// ---------------------------------------------------------------------------
__global__ __launch_bounds__(256) void flash_attn(
    const unsigned short* __restrict__ Q, const unsigned short* __restrict__ KV,
    const unsigned short* __restrict__ Vt, unsigned short* __restrict__ O) {
  constexpr int S = 2048;
  const int tid = threadIdx.x, lane = tid & 63, w = tid >> 6;
  const int g = lane >> 4, lcol = lane & 15;
  const int wg = blockIdx.x;              // 0..511
  const int x8 = wg & 7, q64 = wg >> 3;   // q64 0..63
  const int p = q64 & 15, hi = q64 >> 4;
  const int bh = x8 * 4 + hi;             // 0..31
  const int b = bh >> 4, h = bh & 15;
  const long kvrow0 = (long)b * S;
  const int hd0 = h * 128;

  __shared__ __align__(16) unsigned short Kl[64 * 128];   // [k][d] swizzled
  __shared__ __align__(16) unsigned short Vl[128 * 64];   // [d][k] swizzled
  __shared__ __align__(16) unsigned short Pl[4 * 16 * 72];

  const float kscale = 0.08838834764831845f * 1.4426950408889634f; // /sqrt(128)*log2e

  for (int ti = 0; ti < 2; ti++) {
    const int t = ti ? (31 - p) : p;
    const int qbase = t * 64;
    bf16x8 qf[4];
#pragma unroll
    for (int dc = 0; dc < 4; dc++)
      qf[dc] = *reinterpret_cast<const bf16x8*>(
          Q + (kvrow0 + qbase + w * 16 + lcol) * 2048 + hd0 + dc * 32 + g * 8);
    f32x4 oacc[8] = {};
    float mst[4] = {NEG_INF, NEG_INF, NEG_INF, NEG_INF};
    float lst[4] = {0.f, 0.f, 0.f, 0.f};
    const int nk = t + 1;
    for (int kt = 0; kt < nk; kt++) {
      const int kv0 = kt * 64;
      __syncthreads();
#pragma unroll
      for (int i = 0; i < 4; i++) {
        const int o16 = i * 256 + tid;
        const int kr = o16 >> 4, ks = o16 & 15;
        GLDS16(KV + (kvrow0 + kv0 + kr) * 4096 + hd0 + 8 * (ks ^ (kr & 7)),
               Kl + o16 * 8);
        const int vd = o16 >> 3, vs = o16 & 7;
        GLDS16(Vt + ((long)bh * 128 + vd) * 2048 + kv0 + 8 * (vs ^ (vd & 7)),
               Vl + o16 * 8);
      }
      __syncthreads();
      // QK^T: 16q x 64k
      f32x4 sc[4] = {};
      __builtin_amdgcn_s_setprio(1);
#pragma unroll
      for (int dc = 0; dc < 4; dc++) {
#pragma unroll
        for (int c = 0; c < 4; c++) {
          const bf16x8 kf = *reinterpret_cast<const bf16x8*>(
              Kl + (c * 16 + lcol) * 128 + 8 * ((4 * dc + g) ^ (lcol & 7)));
          sc[c] = __builtin_amdgcn_mfma_f32_16x16x32_bf16(qf[dc], kf, sc[c], 0, 0, 0);
        }
      }
      __builtin_amdgcn_s_setprio(0);
      float s[4][4];
      const int qrow = qbase + w * 16 + g * 4;
      if (kt == nk - 1) {
#pragma unroll
        for (int c = 0; c < 4; c++) {
          const int col = kv0 + c * 16 + lcol;
#pragma unroll
          for (int r = 0; r < 4; r++)
            s[c][r] = (col <= qrow + r) ? sc[c][r] * kscale : NEG_INF;
        }
      } else {
#pragma unroll
        for (int c = 0; c < 4; c++)
#pragma unroll
          for (int r = 0; r < 4; r++) s[c][r] = sc[c][r] * kscale;
      }
      float pm[4];
#pragma unroll
      for (int r = 0; r < 4; r++) {
        float mx = fmaxf(fmaxf(s[0][r], s[1][r]), fmaxf(s[2][r], s[3][r]));
        mx = fmaxf(mx, __shfl_xor(mx, 1));
        mx = fmaxf(mx, __shfl_xor(mx, 2));
        mx = fmaxf(mx, __shfl_xor(mx, 4));
        mx = fmaxf(mx, __shfl_xor(mx, 8));
        pm[r] = mx;
      }
      bool need = false;
#pragma unroll
      for (int r = 0; r < 4; r++) need = need || (pm[r] > mst[r] + 11.5f);
      if (__any(need)) {
#pragma unroll
        for (int r = 0; r < 4; r++) {
          const float mnew = fmaxf(mst[r], pm[r]);
          const float corr = exp2f(mst[r] - mnew);
          mst[r] = mnew;
          lst[r] *= corr;
#pragma unroll
          for (int db = 0; db < 8; db++) oacc[db][r] *= corr;
        }
      }
#pragma unroll
      for (int r = 0; r < 4; r++) {
        float ps = 0.f;
#pragma unroll
        for (int c = 0; c < 4; c++) {
          const float pv = exp2f(s[c][r] - mst[r]);
          Pl[(w * 16 + g * 4 + r) * 72 + c * 16 + lcol] = f2bf(pv);
          ps += pv;
        }
        ps += __shfl_xor(ps, 1); ps += __shfl_xor(ps, 2);
        ps += __shfl_xor(ps, 4); ps += __shfl_xor(ps, 8);
        lst[r] += ps;
      }
      __builtin_amdgcn_s_setprio(1);
#pragma unroll
      for (int kk = 0; kk < 2; kk++) {
        const bf16x8 pf = *reinterpret_cast<const bf16x8*>(
            Pl + (w * 16 + lcol) * 72 + kk * 32 + g * 8);
#pragma unroll
        for (int db = 0; db < 8; db++) {
          const bf16x8 vf = *reinterpret_cast<const bf16x8*>(
              Vl + (db * 16 + lcol) * 64 + 8 * ((4 * kk + g) ^ (lcol & 7)));
          oacc[db] = __builtin_amdgcn_mfma_f32_16x16x32_bf16(pf, vf, oacc[db], 0, 0, 0);
        }
      }
      __builtin_amdgcn_s_setprio(0);
    }
#pragma unroll
    for (int db = 0; db < 8; db++)
#pragma unroll
      for (int r = 0; r < 4; r++) {
        const int qi = qbase + w * 16 + g * 4 + r;
        O[(kvrow0 + qi) * 2048 + hd0 + db * 16 + lcol] = f2bf(oacc[db][r] / lst[r]);
      }
  }
}

// ---------------------------------------------------------------------------
// launch
// ---------------------------------------------------------------------------
extern "C" void kernel_launch(void* const* d_in, const int* in_sizes, int n_in,
                              void* d_out, int out_size, void* d_ws, size_t ws_size,
                              hipStream_t stream) {
  (void)in_sizes; (void)n_in; (void)out_size; (void)ws_size;
  const float* x     = (const float*)d_in[0];
  const float* W_dq  = (const float*)d_in[1];
  const float* W_uq  = (const float*)d_in[2];
  const float* qlng  = (const float*)d_in[3];
  const float* qlnb  = (const float*)d_in[4];
  const float* W_dkv = (const float*)d_in[5];
  const float* W_ukv = (const float*)d_in[6];
  const float* klng  = (const float*)d_in[7];
  const float* klnb  = (const float*)d_in[8];
  const float* W_o   = (const float*)d_in[9];
  const float* n1g   = (const float*)d_in[10];
  const float* n1b   = (const float*)d_in[11];
  const float* n2g   = (const float*)d_in[12];
  const float* n2b   = (const float*)d_in[13];
  const float* fc1w  = (const float*)d_in[14];
  const float* fc1b  = (const float*)d_in[15];
  const float* fc2w  = (const float*)d_in[16];
  const float* fc2b  = (const float*)d_in[17];
  float* out = (float*)d_out;

  char* ws = (char*)d_ws;
  // region A [0,32M): normed -> Obuf -> fc2bb
  unsigned short* normed = (unsigned short*)(ws + 0);
  unsigned short* Obuf   = (unsigned short*)(ws + 0);
  unsigned short* fc2bb  = (unsigned short*)(ws + 0);
  // region B [32M,64M): cqkv_pre -> KV -> fc1bb -> fc2part
  float*          cqkv_pre = (float*)(ws + 33554432);
  unsigned short* KV       = (unsigned short*)(ws + 33554432);
  unsigned short* fc1bb    = (unsigned short*)(ws + 33554432);
  unsigned short* fc2part  = (unsigned short*)(ws + 33554432);
  // region C [64M,68M): cq
  unsigned short* cq  = (unsigned short*)(ws + 67108864);
  // region D [68M,84.7M): Qb -> h1
  unsigned short* Qb = (unsigned short*)(ws + 71303168);
  unsigned short* h1 = (unsigned short*)(ws + 71303168);
  // region E [84M,117.6M): ckv (early) -> x2 (late)
  unsigned short* ckv = (unsigned short*)(ws + 88080384);
  float* x2           = (float*)(ws + 88080384);
  // region F [116M,180M): Vt -> wopart -> hmid
  unsigned short* Vtb    = (unsigned short*)(ws + 121634816);
  unsigned short* wopart = (unsigned short*)(ws + 121634816);
  unsigned short* hmid   = (unsigned short*)(ws + 121634816);
  // region G [180M,...): transposed/cast weights
  unsigned short* dqkv_t = (unsigned short*)(ws + 188743680);  // 1024 x 2048
  unsigned short* uq_t   = dqkv_t + 2097152;                   // 2048 x 512
  unsigned short* ukv_t  = uq_t + 1048576;                     // 4096 x 512
  unsigned short* wo_b   = ukv_t + 2097152;                    // 2048 x 2048

  const dim3 blk(256);
  const dim3 blk8(512);

  transpose_cast<<<dim3(512 / 32, 2048 / 32), blk, 0, stream>>>(W_dq, dqkv_t, 2048, 512);
  transpose_cast<<<dim3(512 / 32, 2048 / 32), blk, 0, stream>>>(W_dkv, dqkv_t + 512 * 2048, 2048, 512);
  transpose_cast<<<dim3(2048 / 32, 512 / 32), blk, 0, stream>>>(W_uq, uq_t, 512, 2048);
  transpose_cast<<<dim3(4096 / 32, 512 / 32), blk, 0, stream>>>(W_ukv, ukv_t, 512, 4096);
  cast_f32_bf16<<<2048 * 2048 / 1024, blk, 0, stream>>>(W_o, wo_b, 2048 * 2048);

  // LN1
  layernorm_bf16<2048><<<4096, blk, 0, stream>>>(x, n1g, n1b, normed, 2048);
  // cqkv_pre = normed @ [W_dq | W_dkv]
  gemm_bt<false, false, false, false><<<dim3(32, 8), blk, 0, stream>>>(
      normed, dqkv_t, nullptr, nullptr, cqkv_pre, 4096, 1024, 2048);
  layernorm_bf16<512><<<4096, blk, 0, stream>>>(cqkv_pre, qlng, qlnb, cq, 1024);
  layernorm_bf16<512><<<4096, blk, 0, stream>>>(cqkv_pre + 512, klng, klnb, ckv, 1024);
  // Q = cq @ W_uq
  gemm_bt<false, false, false, true><<<dim3(32, 16), blk, 0, stream>>>(
      cq, uq_t, nullptr, nullptr, Qb, 4096, 2048, 512);
  // KV = ckv @ W_ukv
  gemm256p<false, false, true><<<dim3(16, 16), blk8, 0, stream>>>(
      ckv, ukv_t, nullptr, KV, 4096, 4096, 512, 512, 512, 0);
  // V transpose for conflict-free PV fragments
  v_transpose<<<dim3(64, 4, 32), blk, 0, stream>>>(KV, Vtb);
  // attention
  flash_attn<<<dim3(512), blk, 0, stream>>>(Qb, KV, Vtb, Obuf);
  // fc1 weights cast (region B free after attention)
  cast_f32_bf16<<<8192 * 2048 / 1024, blk, 0, stream>>>(fc1w, fc1bb, 8192L * 2048);
  // W_o partials: split-K=2 (Vt dead -> region F)
  gemm256p<false, false, true><<<dim3(16, 8, 2), blk8, 0, stream>>>(
      Obuf, wo_b, nullptr, wopart, 4096, 2048, 2048, 2048, 1024, 1024);
  // fc2 weights cast (region A free after W_o gemm)
  cast_f32_bf16<<<2048 * 8192 / 1024, blk, 0, stream>>>(fc2w, fc2bb, 2048L * 8192);
  // x2 = x + p0 + p1 ; h1 = LN(x2)   (fused)
  combine_ln<<<4096, blk, 0, stream>>>(wopart, x, n2g, n2b, x2, h1, 8388608L);
  // h_mid = relu(h1 @ fc1^T + b1)
  gemm256p<true, true, true><<<dim3(16, 32), blk8, 0, stream>>>(
      h1, fc1bb, fc1b, hmid, 4096, 8192, 2048, 2048, 2048, 0);
  // fc2 partials: split-K=2
  gemm256p<false, false, true><<<dim3(16, 8, 2), blk8, 0, stream>>>(
      hmid, fc2bb, nullptr, fc2part, 4096, 2048, 8192, 8192, 4096, 4096);
  // out = p0 + p1 + b2 + x2
  combine2<true><<<8192, blk, 0, stream>>>(fc2part, fc2b, x2, out, 8388608L);
}

// Round 9
// 582.846 us; speedup vs baseline: 10.1136x; 10.1136x over previous
//
#include <hip/hip_runtime.h>
#include <hip/hip_bf16.h>

// ---------------------------------------------------------------------------
// TransformerDecoderBlock (MLA-style) for MI355X / gfx950
// B=2 S=2048 D=2048 NH=16 DH=128 LAT=512
// ---------------------------------------------------------------------------

#define DEVI __device__ __forceinline__

typedef __attribute__((ext_vector_type(8))) short bf16x8;
typedef __attribute__((ext_vector_type(4))) float f32x4;

DEVI unsigned short f2bf(float f) {
  union { float f; unsigned u; } v; v.f = f;
  unsigned r = v.u + 0x7fffu + ((v.u >> 16) & 1u);
  return (unsigned short)(r >> 16);
}

DEVI float bf2f(unsigned short u) {
  union { unsigned u; float f; } v; v.u = ((unsigned)u) << 16;
  return v.f;
}

#define GLDS16(gp, lp)                                              \
  __builtin_amdgcn_global_load_lds(                                 \
      (__attribute__((address_space(1))) void*)(gp),                \
      (__attribute__((address_space(3))) void*)(lp), 16, 0, 0)

#define NEG_INF (-__builtin_inff())

// ---------------------------------------------------------------------------
// cast fp32 -> bf16 (n multiple of 4)
// ---------------------------------------------------------------------------
__global__ __launch_bounds__(256) void cast_f32_bf16(
    const float* __restrict__ in, unsigned short* __restrict__ out, long n) {
  long i = ((long)blockIdx.x * 256 + threadIdx.x) * 4;
  if (i >= n) return;
  const float4 v = *reinterpret_cast<const float4*>(in + i);
  ushort4 o;
  o.x = f2bf(v.x); o.y = f2bf(v.y); o.z = f2bf(v.z); o.w = f2bf(v.w);
  *reinterpret_cast<ushort4*>(out + i) = o;
}

// ---------------------------------------------------------------------------
// transpose + cast: in (R x C) f32  ->  out (C x R) bf16.  R,C multiples of 32
// ---------------------------------------------------------------------------
__global__ __launch_bounds__(256) void transpose_cast(
    const float* __restrict__ in, unsigned short* __restrict__ out, int R, int C) {
  __shared__ float tile[32][33];
  const int c0 = blockIdx.x * 32, r0 = blockIdx.y * 32;
  const int tx = threadIdx.x & 31, ty = threadIdx.x >> 5;  // ty 0..7
#pragma unroll
  for (int i = 0; i < 32; i += 8)
    tile[ty + i][tx] = in[(long)(r0 + ty + i) * C + c0 + tx];
  __syncthreads();
#pragma unroll
  for (int i = 0; i < 32; i += 8)
    out[(long)(c0 + ty + i) * R + r0 + tx] = f2bf(tile[tx][ty + i]);
}

// ---------------------------------------------------------------------------
// V transpose: KV (B*S x 4096 bf16, V at cols [2048,4096)) ->
//   Vt[bh][d][s]  (32 x 128 x 2048 bf16)
// ---------------------------------------------------------------------------
__global__ __launch_bounds__(256) void v_transpose(
    const unsigned short* __restrict__ KV, unsigned short* __restrict__ Vt) {
  __shared__ unsigned short sh[32][33];
  const int s0 = blockIdx.x * 32, d0 = blockIdx.y * 32, bh = blockIdx.z;
  const int b = bh >> 4, h = bh & 15;
  const int tx = threadIdx.x & 31, ty = threadIdx.x >> 5;  // ty 0..7
#pragma unroll
  for (int i = 0; i < 32; i += 8)
    sh[ty + i][tx] = KV[((long)(b * 2048 + s0 + ty + i)) * 4096 + 2048 + h * 128 + d0 + tx];
  __syncthreads();
#pragma unroll
  for (int i = 0; i < 32; i += 8)
    Vt[((long)(bh * 128 + d0 + ty + i)) * 2048 + s0 + tx] = sh[tx][ty + i];
}

// ---------------------------------------------------------------------------
// block reduce (256 threads = 4 waves)
// ---------------------------------------------------------------------------
DEVI float blockReduceSum(float v) {
  v += __shfl_xor(v, 1);  v += __shfl_xor(v, 2);  v += __shfl_xor(v, 4);
  v += __shfl_xor(v, 8);  v += __shfl_xor(v, 16); v += __shfl_xor(v, 32);
  __shared__ float red[4];
  if ((threadIdx.x & 63) == 0) red[threadIdx.x >> 6] = v;
  __syncthreads();
  v = red[0] + red[1] + red[2] + red[3];
  __syncthreads();
  return v;
}

// ---------------------------------------------------------------------------
// LayerNorm over W cols, one block (256 thr) per row; input row stride ldin.
// f32 in -> bf16 out (out contiguous, stride W)
// ---------------------------------------------------------------------------
template <int W>
__global__ __launch_bounds__(256) void layernorm_bf16(
    const float* __restrict__ in, const float* __restrict__ g,
    const float* __restrict__ b, unsigned short* __restrict__ out, int ldin) {
  constexpr int VPT = W / 256;
  const long row = blockIdx.x;
  const float* x = in + row * ldin;
  float v[VPT];
  float s = 0.f;
#pragma unroll
  for (int i = 0; i < VPT; i++) { v[i] = x[threadIdx.x + i * 256]; s += v[i]; }
  s = blockReduceSum(s);
  const float mean = s * (1.0f / W);
  float s2 = 0.f;
#pragma unroll
  for (int i = 0; i < VPT; i++) { float d = v[i] - mean; s2 += d * d; }
  s2 = blockReduceSum(s2);
  const float rstd = rsqrtf(s2 * (1.0f / W) + 1e-5f);
#pragma unroll
  for (int i = 0; i < VPT; i++) {
    const int c = threadIdx.x + i * 256;
    out[row * W + c] = f2bf((v[i] - mean) * rstd * g[c] + b[c]);
  }
}

// ---------------------------------------------------------------------------
// combine_ln: fused W_o-combine + residual + LayerNorm (W=2048).
//   x2 = x + p0 + p1 ; h1 = LN(x2) * g + b
// ---------------------------------------------------------------------------
__global__ __launch_bounds__(256) void combine_ln(
    const unsigned short* __restrict__ p, const float* __restrict__ xres,
    const float* __restrict__ g, const float* __restrict__ b,
    float* __restrict__ x2, unsigned short* __restrict__ h1, long n) {
  const int c0 = threadIdx.x * 8;
  const long base = (long)blockIdx.x * 2048 + c0;
  float v[8];
  float s = 0.f;
#pragma unroll
  for (int hh = 0; hh < 2; hh++) {
    const long i = base + hh * 4;
    const ushort4 a  = *reinterpret_cast<const ushort4*>(p + i);
    const ushort4 bb = *reinterpret_cast<const ushort4*>(p + n + i);
    const float4 r = *reinterpret_cast<const float4*>(xres + i);
    float4 o;
    o.x = r.x + bf2f(a.x) + bf2f(bb.x);
    o.y = r.y + bf2f(a.y) + bf2f(bb.y);
    o.z = r.z + bf2f(a.z) + bf2f(bb.z);
    o.w = r.w + bf2f(a.w) + bf2f(bb.w);
    *reinterpret_cast<float4*>(x2 + i) = o;
    v[hh * 4 + 0] = o.x; v[hh * 4 + 1] = o.y;
    v[hh * 4 + 2] = o.z; v[hh * 4 + 3] = o.w;
    s += o.x + o.y + o.z + o.w;
  }
  s = blockReduceSum(s);
  const float mean = s * (1.0f / 2048.f);
  float s2 = 0.f;
#pragma unroll
  for (int i = 0; i < 8; i++) { float d = v[i] - mean; s2 += d * d; }
  s2 = blockReduceSum(s2);
  const float rstd = rsqrtf(s2 * (1.0f / 2048.f) + 1e-5f);
#pragma unroll
  for (int hh = 0; hh < 2; hh++) {
    const float4 gv = *reinterpret_cast<const float4*>(g + c0 + hh * 4);
    const float4 bv = *reinterpret_cast<const float4*>(b + c0 + hh * 4);
    ushort4 o;
    o.x = f2bf((v[hh * 4 + 0] - mean) * rstd * gv.x + bv.x);
    o.y = f2bf((v[hh * 4 + 1] - mean) * rstd * gv.y + bv.y);
    o.z = f2bf((v[hh * 4 + 2] - mean) * rstd * gv.z + bv.z);
    o.w = f2bf((v[hh * 4 + 3] - mean) * rstd * gv.w + bv.w);
    *reinterpret_cast<ushort4*>(h1 + base + hh * 4) = o;
  }
}

// ---------------------------------------------------------------------------
// gemm_bt: C(MxN) = A * Bt^T, 128x128 tile, BK=32, 4 waves (for small-N
// GEMMs: merged dq|dkv, Q-up).
// ---------------------------------------------------------------------------
template <bool BIAS, bool RELU, bool RES, bool OBF16>
__global__ __launch_bounds__(256) void gemm_bt(
    const unsigned short* __restrict__ A, const unsigned short* __restrict__ Bt,
    const float* __restrict__ bias, const float* __restrict__ res,
    void* __restrict__ Cout, int M, int N, int K) {
  __shared__ __align__(16) unsigned short As[2][128 * 32];
  __shared__ __align__(16) unsigned short Bs[2][128 * 32];

  const int m0 = blockIdx.x * 128;
  const int n0 = blockIdx.y * 128;
  const int tid = threadIdx.x;
  const int lane = tid & 63, w = tid >> 6;
  const int wr = (w >> 1) * 64, wc = (w & 1) * 64;
  const int lrow = lane & 15, lk = (lane >> 4) * 8;

  f32x4 acc[4][4] = {};

  const int nt = K >> 5;
  const int r_ = (tid * 8) >> 5;      // 0..63
  const int c_ = (tid * 8) & 31;

#define STAGE(buf, t)                                                        \
  {                                                                          \
    const long k0 = (long)(t) * 32;                                          \
    GLDS16(A + (long)(m0 + r_) * K + k0 + c_, &As[buf][tid * 8]);            \
    GLDS16(A + (long)(m0 + 64 + r_) * K + k0 + c_, &As[buf][2048 + tid * 8]);\
    GLDS16(Bt + (long)(n0 + r_) * K + k0 + c_, &Bs[buf][tid * 8]);           \
    GLDS16(Bt + (long)(n0 + 64 + r_) * K + k0 + c_, &Bs[buf][2048 + tid * 8]);\
  }

  STAGE(0, 0)
  __syncthreads();
  int cur = 0;
  for (int t = 0; t < nt; t++) {
    if (t + 1 < nt) STAGE(cur ^ 1, t + 1)
    bf16x8 fa[4], fb[4];
#pragma unroll
    for (int i = 0; i < 4; i++) {
      fa[i] = *reinterpret_cast<const bf16x8*>(&As[cur][(wr + i * 16 + lrow) * 32 + lk]);
      fb[i] = *reinterpret_cast<const bf16x8*>(&Bs[cur][(wc + i * 16 + lrow) * 32 + lk]);
    }
#pragma unroll
    for (int i = 0; i < 4; i++)
#pragma unroll
      for (int j = 0; j < 4; j++)
        acc[i][j] = __builtin_amdgcn_mfma_f32_16x16x32_bf16(fa[i], fb[j], acc[i][j], 0, 0, 0);
    __syncthreads();
    cur ^= 1;
  }
#undef STAGE

#pragma unroll
  for (int i = 0; i < 4; i++) {
#pragma unroll
    for (int j = 0; j < 4; j++) {
      const int row = m0 + wr + i * 16 + ((lane >> 4) << 2);
      const int col = n0 + wc + j * 16 + lrow;
      float bv = 0.f;
      if (BIAS) bv = bias[col];
#pragma unroll
      for (int r = 0; r < 4; r++) {
        float v = acc[i][j][r];
        const long idx = (long)(row + r) * N + col;
        if (BIAS) v += bv;
        if (RELU) v = fmaxf(v, 0.f);
        if (RES) v += res[idx];
        if (OBF16) ((unsigned short*)Cout)[idx] = f2bf(v);
        else       ((float*)Cout)[idx] = v;
      }
    }
  }
}

// ---------------------------------------------------------------------------
// gemm256p: 4-phase pipelined 256x256 GEMM, BK=64, 8 waves (512 thr).
// REVERTED to the R6 structure (best measured: 0 bank conflicts, no spill,
// MfmaUtil 48%). R8's X/Y register double-buffer spilled to scratch (12.9 GB
// traffic) — do not reintroduce.
// Wave mapping (quadrant-dynamic): each wave owns a 64x32 sub-tile of EVERY
// 128x128 output quadrant (sr=(w>>2)*64, sc=(w&3)*32). Phase p computes one
// quadrant over full K=64: P1=(0,0) P2=(1,0) P3=(1,1) P4=(0,1).
// Staging: one half-tile (128 rows x 64 k, 2 glds/thread) per phase, order
// S1=Ah0 S2=Bh0 S3=Ah1 S4=Bh1 for tile t+1 -> phase p of tile t+1 consumes
// exactly S_p. vmcnt(4) at ends of P1,P2,P4; no sync at P3 (see R6 ledger).
// Swizzle: 16B slot s of row r holds k-seg s ^ ((r>>1)&3) (measured 0 confl).
// NEW (T1): bijective XCD swizzle of the linearized block index — groups
// blocks sharing a B-panel (same by) onto one XCD so 4 x 1MB B-panels live
// in that XCD's 4MB L2. Requires nwg % 8 == 0 (all launches satisfy).
// gyShift = log2(gridDim.y); gridDim.x must be 16.
// blockIdx.z = split-K slice: A/Bt advanced by z*kOff, C by z*M*N.
// ---------------------------------------------------------------------------
template <bool BIAS, bool RELU, bool OBF16>
__global__ __launch_bounds__(512, 1) void gemm256p(
    const unsigned short* __restrict__ A, const unsigned short* __restrict__ Bt,
    const float* __restrict__ bias, void* __restrict__ Cout,
    int M, int N, int lda, int ldb, int kLen, long kOff, int gyShift) {
  __shared__ __align__(16) unsigned short L[2][2][2][256 * 32];

  // --- XCD-aware bijective remap of the linear workgroup id ---
  const int gy = 1 << gyShift;
  const int nwg = (16 << gyShift) * gridDim.z;
  const int lid = blockIdx.x + 16 * (blockIdx.y + gy * blockIdx.z);
  int t0 = (lid & 7) * (nwg >> 3) + (lid >> 3);
  const int bx = t0 & 15;
  const int rest = t0 >> 4;
  const int by = rest & (gy - 1);
  const int bz = rest >> gyShift;

  const int m0 = bx * 256, n0 = by * 256;
  const long ka = (long)bz * kOff;
  const int tid = threadIdx.x;
  const int lane = tid & 63, w = tid >> 6;
  const int sr = (w >> 2) * 64, sc = (w & 3) * 32;
  const int g = lane >> 4, lrow = lane & 15;
  const int r_ = tid >> 2, s_ = tid & 3;

  f32x4 acc[2][2][4][2] = {};
  const int nt = kLen >> 6;

#define STG1(bb, ab, h, kh, t, P, base0, ld)                                   \
  {                                                                            \
    const long k0 = ka + (long)(t) * 64 + (kh) * 32;                           \
    const int rr = (h) * 128 + r_;                                             \
    GLDS16((P) + (long)((base0) + rr) * (ld) + k0 + ((s_ ^ ((rr >> 1) & 3)) << 3), \
           &L[bb][ab][kh][((h) * 512 + tid) * 8]);                             \
  }
#define STG_A(bb, h, t) STG1(bb, 0, h, 0, t, A, m0, lda) STG1(bb, 0, h, 1, t, A, m0, lda)
#define STG_B(bb, h, t) STG1(bb, 1, h, 0, t, Bt, n0, ldb) STG1(bb, 1, h, 1, t, Bt, n0, ldb)

#define RD(dst, ab, kh, row)                                                   \
  dst = *reinterpret_cast<const bf16x8*>(                                      \
      &L[bu][ab][kh][((row) * 4 + (g ^ (((row) >> 1) & 3))) * 8]);

#define PH_READS(a, b)                                                         \
  bf16x8 fa[2][4], fb[2][2];                                                   \
  _Pragma("unroll")                                                            \
  for (int kh = 0; kh < 2; kh++) {                                             \
    _Pragma("unroll")                                                          \
    for (int i = 0; i < 4; i++) {                                              \
      const int rr = (a) * 128 + sr + i * 16 + lrow;                           \
      RD(fa[kh][i], 0, kh, rr)                                                 \
    }                                                                          \
    _Pragma("unroll")                                                          \
    for (int j = 0; j < 2; j++) {                                              \
      const int rr = (b) * 128 + sc + j * 16 + lrow;                           \
      RD(fb[kh][j], 1, kh, rr)                                                 \
    }                                                                          \
  }

#define PH_MFMA(a, b)                                                          \
  __builtin_amdgcn_s_setprio(1);                                               \
  _Pragma("unroll")                                                            \
  for (int kh = 0; kh < 2; kh++)                                               \
    _Pragma("unroll")                                                          \
    for (int i = 0; i < 4; i++)                                                \
      _Pragma("unroll")                                                        \
      for (int j = 0; j < 2; j++)                                              \
        acc[a][b][i][j] = __builtin_amdgcn_mfma_f32_16x16x32_bf16(             \
            fa[kh][i], fb[kh][j], acc[a][b][i][j], 0, 0, 0);                   \
  __builtin_amdgcn_s_setprio(0);

  // prologue: tile 0 -> buf 0, full drain (once per kernel)
  STG_A(0, 0, 0) STG_B(0, 0, 0) STG_A(0, 1, 0) STG_B(0, 1, 0)
  asm volatile("s_waitcnt vmcnt(0)\n\ts_barrier" ::: "memory");

  int t = 0;
  for (; t < nt - 1; t++) {
    const int bu = t & 1, bn = bu ^ 1;
    {  // P1: quad(0,0); stage Ah0(t+1)
      PH_READS(0, 0)
      STG_A(bn, 0, t + 1)
      PH_MFMA(0, 0)
      asm volatile("s_waitcnt vmcnt(4)\n\ts_barrier" ::: "memory");
    }
    {  // P2: quad(1,0); stage Bh0(t+1)
      PH_READS(1, 0)
      STG_B(bn, 0, t + 1)
      PH_MFMA(1, 0)
      asm volatile("s_waitcnt vmcnt(4)\n\ts_barrier" ::: "memory");
    }
    {  // P3: quad(1,1); stage Ah1(t+1); no sync needed
      PH_READS(1, 1)
      STG_A(bn, 1, t + 1)
      PH_MFMA(1, 1)
    }
    {  // P4: quad(0,1); stage Bh1(t+1)
      PH_READS(0, 1)
      STG_B(bn, 1, t + 1)
      PH_MFMA(0, 1)
      asm volatile("s_waitcnt vmcnt(4)\n\ts_barrier" ::: "memory");
    }
  }
  {  // last tile: no staging; entering outstanding = {Ah1,Bh1} = 4 loads
    const int bu = t & 1;
    {
      PH_READS(0, 0)
      PH_MFMA(0, 0)
      asm volatile("s_waitcnt vmcnt(2)\n\ts_barrier" ::: "memory");
    }
    {
      PH_READS(1, 0)
      PH_MFMA(1, 0)
      asm volatile("s_waitcnt vmcnt(0)\n\ts_barrier" ::: "memory");
    }
    {
      PH_READS(1, 1)
      PH_MFMA(1, 1)
    }
    {
      PH_READS(0, 1)
      PH_MFMA(0, 1)
    }
  }
#undef STG1
#undef STG_A
#undef STG_B
#undef RD
#undef PH_READS
#undef PH_MFMA

  const long zoff = (long)bz * (long)M * (long)N;
#pragma unroll
  for (int a = 0; a < 2; a++) {
#pragma unroll
    for (int b = 0; b < 2; b++) {
#pragma unroll
      for (int i = 0; i < 4; i++) {
#pragma unroll
        for (int j = 0; j < 2; j++) {
          const int row = m0 + a * 128 + sr + i * 16 + g * 4;
          const int col = n0 + b * 128 + sc + j * 16 + lrow;
          float bv = 0.f;
          if (BIAS) bv = bias[col];
#pragma unroll
          for (int r = 0; r < 4; r++) {
            float v = acc[a][b][i][j][r];
            if (BIAS) v += bv;
            if (RELU) v = fmaxf(v, 0.f);
            const long idx = zoff + (long)(row + r) * N + col;
            if (OBF16) ((unsigned short*)Cout)[idx] = f2bf(v);
            else       ((float*)Cout)[idx] = v;
          }
        }
      }
    }
  }
}

// ---------------------------------------------------------------------------
// combine split-K partials: out = p0 + p1 [+ bias[col]] + res  (f32)
// N = 2048 fixed (bias index = i & 2047), n = M*N, 4 elements/thread
// ---------------------------------------------------------------------------
template <bool BIAS>
__global__ __launch_bounds__(256) void combine2(
    const unsigned short* __restrict__ p, const float* __restrict__ bias,
    const float* __restrict__ res, float* __restrict__ out, long n) {
  const long i = ((long)blockIdx.x * 256 + threadIdx.x) * 4;
  if (i >= n) return;
  const ushort4 a = *reinterpret_cast<const ushort4*>(p + i);
  const ushort4 b = *reinterpret_cast<const ushort4*>(p + n + i);
  const float4 r = *reinterpret_cast<const float4*>(res + i);
  float4 o;
  o.x = bf2f(a.x) + bf2f(b.x) + r.x;
  o.y = bf2f(a.y) + bf2f(b.y) + r.y;
  o.z = bf2f(a.z) + bf2f(b.z) + r.z;
  o.w = bf2f(a.w) + bf2f(b.w) + r.w;
  if (BIAS) {
    const int col = (int)(i & 2047);
    const float4 bv = *reinterpret_cast<const float4*>(bias + col);
    o.x += bv.x; o.y += bv.y; o.z += bv.z; o.w += bv.w;
  }
  *reinterpret_cast<float4*>(out + i) = o;
}

// ---------------------------------------------------------------------------
// Causal flash attention, KVBLK=64, global_load_lds + XOR-swizzled tiles.
// ---------------------------------------------------------------------------
__global__ __launch_bounds__(256) void flash_attn(
    const unsigned short* __restrict__ Q, const unsigned short* __restrict__ KV,
    const unsigned short* __restrict__ Vt, unsigned short* __restrict__ O) {
  constexpr int S = 2048;
  const int tid = threadIdx.x, lane = tid & 63, w = tid >> 6;
  const int g = lane >> 4, lcol = lane & 15;
  const int wg = blockIdx.x;              // 0..511
  const int x8 = wg & 7, q64 = wg >> 3;   // q64 0..63
  const int p = q64 & 15, hi = q64 >> 4;
  const int bh = x8 * 4 + hi;             // 0..31
  const int b = bh >> 4, h = bh & 15;
  const long kvrow0 = (long)b * S;
  const int hd0 = h * 128;

  __shared__ __align__(16) unsigned short Kl[64 * 128];   // [k][d] swizzled
  __shared__ __align__(16) unsigned short Vl[128 * 64];   // [d][k] swizzled
  __shared__ __align__(16) unsigned short Pl[4 * 16 * 72];

  const float kscale = 0.08838834764831845f * 1.4426950408889634f; // /sqrt(128)*log2e

  for (int ti = 0; ti < 2; ti++) {
    const int t = ti ? (31 - p) : p;
    const int qbase = t * 64;
    bf16x8 qf[4];
#pragma unroll
    for (int dc = 0; dc < 4; dc++)
      qf[dc] = *reinterpret_cast<const bf16x8*>(
          Q + (kvrow0 + qbase + w * 16 + lcol) * 2048 + hd0 + dc * 32 + g * 8);
    f32x4 oacc[8] = {};
    float mst[4] = {NEG_INF, NEG_INF, NEG_INF, NEG_INF};
    float lst[4] = {0.f, 0.f, 0.f, 0.f};
    const int nk = t + 1;
    for (int kt = 0; kt < nk; kt++) {
      const int kv0 = kt * 64;
      __syncthreads();
#pragma unroll
      for (int i = 0; i < 4; i++) {
        const int o16 = i * 256 + tid;
        const int kr = o16 >> 4, ks = o16 & 15;
        GLDS16(KV + (kvrow0 + kv0 + kr) * 4096 + hd0 + 8 * (ks ^ (kr & 7)),
               Kl + o16 * 8);
        const int vd = o16 >> 3, vs = o16 & 7;
        GLDS16(Vt + ((long)bh * 128 + vd) * 2048 + kv0 + 8 * (vs ^ (vd & 7)),
               Vl + o16 * 8);
      }
      __syncthreads();
      // QK^T: 16q x 64k
      f32x4 sc[4] = {};
      __builtin_amdgcn_s_setprio(1);
#pragma unroll
      for (int dc = 0; dc < 4; dc++) {
#pragma unroll
        for (int c = 0; c < 4; c++) {
          const bf16x8 kf = *reinterpret_cast<const bf16x8*>(
              Kl + (c * 16 + lcol) * 128 + 8 * ((4 * dc + g) ^ (lcol & 7)));
          sc[c] = __builtin_amdgcn_mfma_f32_16x16x32_bf16(qf[dc], kf, sc[c], 0, 0, 0);
        }
      }
      __builtin_amdgcn_s_setprio(0);
      float s[4][4];
      const int qrow = qbase + w * 16 + g * 4;
      if (kt == nk - 1) {
#pragma unroll
        for (int c = 0; c < 4; c++) {
          const int col = kv0 + c * 16 + lcol;
#pragma unroll
          for (int r = 0; r < 4; r++)
            s[c][r] = (col <= qrow + r) ? sc[c][r] * kscale : NEG_INF;
        }
      } else {
#pragma unroll
        for (int c = 0; c < 4; c++)
#pragma unroll
          for (int r = 0; r < 4; r++) s[c][r] = sc[c][r] * kscale;
      }
      float pm[4];
#pragma unroll
      for (int r = 0; r < 4; r++) {
        float mx = fmaxf(fmaxf(s[0][r], s[1][r]), fmaxf(s[2][r], s[3][r]));
        mx = fmaxf(mx, __shfl_xor(mx, 1));
        mx = fmaxf(mx, __shfl_xor(mx, 2));
        mx = fmaxf(mx, __shfl_xor(mx, 4));
        mx = fmaxf(mx, __shfl_xor(mx, 8));
        pm[r] = mx;
      }
      bool need = false;
#pragma unroll
      for (int r = 0; r < 4; r++) need = need || (pm[r] > mst[r] + 11.5f);
      if (__any(need)) {
#pragma unroll
        for (int r = 0; r < 4; r++) {
          const float mnew = fmaxf(mst[r], pm[r]);
          const float corr = exp2f(mst[r] - mnew);
          mst[r] = mnew;
          lst[r] *= corr;
#pragma unroll
          for (int db = 0; db < 8; db++) oacc[db][r] *= corr;
        }
      }
#pragma unroll
      for (int r = 0; r < 4; r++) {
        float ps = 0.f;
#pragma unroll
        for (int c = 0; c < 4; c++) {
          const float pv = exp2f(s[c][r] - mst[r]);
          Pl[(w * 16 + g * 4 + r) * 72 + c * 16 + lcol] = f2bf(pv);
          ps += pv;
        }
        ps += __shfl_xor(ps, 1); ps += __shfl_xor(ps, 2);
        ps += __shfl_xor(ps, 4); ps += __shfl_xor(ps, 8);
        lst[r] += ps;
      }
      __builtin_amdgcn_s_setprio(1);
#pragma unroll
      for (int kk = 0; kk < 2; kk++) {
        const bf16x8 pf = *reinterpret_cast<const bf16x8*>(
            Pl + (w * 16 + lcol) * 72 + kk * 32 + g * 8);
#pragma unroll
        for (int db = 0; db < 8; db++) {
          const bf16x8 vf = *reinterpret_cast<const bf16x8*>(
              Vl + (db * 16 + lcol) * 64 + 8 * ((4 * kk + g) ^ (lcol & 7)));
          oacc[db] = __builtin_amdgcn_mfma_f32_16x16x32_bf16(pf, vf, oacc[db], 0, 0, 0);
        }
      }
      __builtin_amdgcn_s_setprio(0);
    }
#pragma unroll
    for (int db = 0; db < 8; db++)
#pragma unroll
      for (int r = 0; r < 4; r++) {
        const int qi = qbase + w * 16 + g * 4 + r;
        O[(kvrow0 + qi) * 2048 + hd0 + db * 16 + lcol] = f2bf(oacc[db][r] / lst[r]);
      }
  }
}

// ---------------------------------------------------------------------------
// launch
// ---------------------------------------------------------------------------
extern "C" void kernel_launch(void* const* d_in, const int* in_sizes, int n_in,
                              void* d_out, int out_size, void* d_ws, size_t ws_size,
                              hipStream_t stream) {
  (void)in_sizes; (void)n_in; (void)out_size; (void)ws_size;
  const float* x     = (const float*)d_in[0];
  const float* W_dq  = (const float*)d_in[1];
  const float* W_uq  = (const float*)d_in[2];
  const float* qlng  = (const float*)d_in[3];
  const float* qlnb  = (const float*)d_in[4];
  const float* W_dkv = (const float*)d_in[5];
  const float* W_ukv = (const float*)d_in[6];
  const float* klng  = (const float*)d_in[7];
  const float* klnb  = (const float*)d_in[8];
  const float* W_o   = (const float*)d_in[9];
  const float* n1g   = (const float*)d_in[10];
  const float* n1b   = (const float*)d_in[11];
  const float* n2g   = (const float*)d_in[12];
  const float* n2b   = (const float*)d_in[13];
  const float* fc1w  = (const float*)d_in[14];
  const float* fc1b  = (const float*)d_in[15];
  const float* fc2w  = (const float*)d_in[16];
  const float* fc2b  = (const float*)d_in[17];
  float* out = (float*)d_out;

  char* ws = (char*)d_ws;
  // region A [0,32M): normed -> Obuf -> fc2bb
  unsigned short* normed = (unsigned short*)(ws + 0);
  unsigned short* Obuf   = (unsigned short*)(ws + 0);
  unsigned short* fc2bb  = (unsigned short*)(ws + 0);
  // region B [32M,64M): cqkv_pre -> KV -> fc1bb -> fc2part
  float*          cqkv_pre = (float*)(ws + 33554432);
  unsigned short* KV       = (unsigned short*)(ws + 33554432);
  unsigned short* fc1bb    = (unsigned short*)(ws + 33554432);
  unsigned short* fc2part  = (unsigned short*)(ws + 33554432);
  // region C [64M,68M): cq
  unsigned short* cq  = (unsigned short*)(ws + 67108864);
  // region D [68M,84.7M): Qb -> h1
  unsigned short* Qb = (unsigned short*)(ws + 71303168);
  unsigned short* h1 = (unsigned short*)(ws + 71303168);
  // region E [84M,117.6M): ckv (early) -> x2 (late)
  unsigned short* ckv = (unsigned short*)(ws + 88080384);
  float* x2           = (float*)(ws + 88080384);
  // region F [116M,180M): Vt -> wopart -> hmid
  unsigned short* Vtb    = (unsigned short*)(ws + 121634816);
  unsigned short* wopart = (unsigned short*)(ws + 121634816);
  unsigned short* hmid   = (unsigned short*)(ws + 121634816);
  // region G [180M,...): transposed/cast weights
  unsigned short* dqkv_t = (unsigned short*)(ws + 188743680);  // 1024 x 2048
  unsigned short* uq_t   = dqkv_t + 2097152;                   // 2048 x 512
  unsigned short* ukv_t  = uq_t + 1048576;                     // 4096 x 512
  unsigned short* wo_b   = ukv_t + 2097152;                    // 2048 x 2048

  const dim3 blk(256);
  const dim3 blk8(512);

  transpose_cast<<<dim3(512 / 32, 2048 / 32), blk, 0, stream>>>(W_dq, dqkv_t, 2048, 512);
  transpose_cast<<<dim3(512 / 32, 2048 / 32), blk, 0, stream>>>(W_dkv, dqkv_t + 512 * 2048, 2048, 512);
  transpose_cast<<<dim3(2048 / 32, 512 / 32), blk, 0, stream>>>(W_uq, uq_t, 512, 2048);
  transpose_cast<<<dim3(4096 / 32, 512 / 32), blk, 0, stream>>>(W_ukv, ukv_t, 512, 4096);
  cast_f32_bf16<<<2048 * 2048 / 1024, blk, 0, stream>>>(W_o, wo_b, 2048 * 2048);

  // LN1
  layernorm_bf16<2048><<<4096, blk, 0, stream>>>(x, n1g, n1b, normed, 2048);
  // cqkv_pre = normed @ [W_dq | W_dkv]
  gemm_bt<false, false, false, false><<<dim3(32, 8), blk, 0, stream>>>(
      normed, dqkv_t, nullptr, nullptr, cqkv_pre, 4096, 1024, 2048);
  layernorm_bf16<512><<<4096, blk, 0, stream>>>(cqkv_pre, qlng, qlnb, cq, 1024);
  layernorm_bf16<512><<<4096, blk, 0, stream>>>(cqkv_pre + 512, klng, klnb, ckv, 1024);
  // Q = cq @ W_uq
  gemm_bt<false, false, false, true><<<dim3(32, 16), blk, 0, stream>>>(
      cq, uq_t, nullptr, nullptr, Qb, 4096, 2048, 512);
  // KV = ckv @ W_ukv   (gy=16 -> shift 4)
  gemm256p<false, false, true><<<dim3(16, 16), blk8, 0, stream>>>(
      ckv, ukv_t, nullptr, KV, 4096, 4096, 512, 512, 512, 0, 4);
  // V transpose for conflict-free PV fragments
  v_transpose<<<dim3(64, 4, 32), blk, 0, stream>>>(KV, Vtb);
  // attention
  flash_attn<<<dim3(512), blk, 0, stream>>>(Qb, KV, Vtb, Obuf);
  // fc1 weights cast (region B free after attention)
  cast_f32_bf16<<<8192 * 2048 / 1024, blk, 0, stream>>>(fc1w, fc1bb, 8192L * 2048);
  // W_o partials: split-K=2 (gy=8 -> shift 3)
  gemm256p<false, false, true><<<dim3(16, 8, 2), blk8, 0, stream>>>(
      Obuf, wo_b, nullptr, wopart, 4096, 2048, 2048, 2048, 1024, 1024, 3);
  // fc2 weights cast (region A free after W_o gemm)
  cast_f32_bf16<<<2048 * 8192 / 1024, blk, 0, stream>>>(fc2w, fc2bb, 2048L * 8192);
  // x2 = x + p0 + p1 ; h1 = LN(x2)   (fused)
  combine_ln<<<4096, blk, 0, stream>>>(wopart, x, n2g, n2b, x2, h1, 8388608L);
  // h_mid = relu(h1 @ fc1^T + b1)   (gy=32 -> shift 5)
  gemm256p<true, true, true><<<dim3(16, 32), blk8, 0, stream>>>(
      h1, fc1bb, fc1b, hmid, 4096, 8192, 2048, 2048, 2048, 0, 5);
  // fc2 partials: split-K=2 (gy=8 -> shift 3)
  gemm256p<false, false, true><<<dim3(16, 8, 2), blk8, 0, stream>>>(
      hmid, fc2bb, nullptr, fc2part, 4096, 2048, 8192, 8192, 4096, 4096, 3);
  // out = p0 + p1 + b2 + x2
  combine2<true><<<8192, blk, 0, stream>>>(fc2part, fc2b, x2, out, 8388608L);
}

// Round 10
// 560.648 us; speedup vs baseline: 10.5140x; 1.0396x over previous
//
#include <hip/hip_runtime.h>
#include <hip/hip_bf16.h>

// ---------------------------------------------------------------------------
// TransformerDecoderBlock (MLA-style) for MI355X / gfx950
// B=2 S=2048 D=2048 NH=16 DH=128 LAT=512
// ---------------------------------------------------------------------------

#define DEVI __device__ __forceinline__

typedef __attribute__((ext_vector_type(8))) short bf16x8;
typedef __attribute__((ext_vector_type(4))) float f32x4;

DEVI unsigned short f2bf(float f) {
  union { float f; unsigned u; } v; v.f = f;
  unsigned r = v.u + 0x7fffu + ((v.u >> 16) & 1u);
  return (unsigned short)(r >> 16);
}

DEVI float bf2f(unsigned short u) {
  union { unsigned u; float f; } v; v.u = ((unsigned)u) << 16;
  return v.f;
}

#define GLDS16(gp, lp)                                              \
  __builtin_amdgcn_global_load_lds(                                 \
      (__attribute__((address_space(1))) void*)(gp),                \
      (__attribute__((address_space(3))) void*)(lp), 16, 0, 0)

#define NEG_INF (-__builtin_inff())

// ---------------------------------------------------------------------------
// cast fp32 -> bf16 (n multiple of 4)
// ---------------------------------------------------------------------------
__global__ __launch_bounds__(256) void cast_f32_bf16(
    const float* __restrict__ in, unsigned short* __restrict__ out, long n) {
  long i = ((long)blockIdx.x * 256 + threadIdx.x) * 4;
  if (i >= n) return;
  const float4 v = *reinterpret_cast<const float4*>(in + i);
  ushort4 o;
  o.x = f2bf(v.x); o.y = f2bf(v.y); o.z = f2bf(v.z); o.w = f2bf(v.w);
  *reinterpret_cast<ushort4*>(out + i) = o;
}

// ---------------------------------------------------------------------------
// transpose + cast: in (R x C) f32  ->  out (C x R) bf16.  R,C multiples of 32
// ---------------------------------------------------------------------------
__global__ __launch_bounds__(256) void transpose_cast(
    const float* __restrict__ in, unsigned short* __restrict__ out, int R, int C) {
  __shared__ float tile[32][33];
  const int c0 = blockIdx.x * 32, r0 = blockIdx.y * 32;
  const int tx = threadIdx.x & 31, ty = threadIdx.x >> 5;  // ty 0..7
#pragma unroll
  for (int i = 0; i < 32; i += 8)
    tile[ty + i][tx] = in[(long)(r0 + ty + i) * C + c0 + tx];
  __syncthreads();
#pragma unroll
  for (int i = 0; i < 32; i += 8)
    out[(long)(c0 + ty + i) * R + r0 + tx] = f2bf(tile[tx][ty + i]);
}

// ---------------------------------------------------------------------------
// V transpose: KV (B*S x 4096 bf16, V at cols [2048,4096)) ->
//   Vt[bh][d][s]  (32 x 128 x 2048 bf16)
// ---------------------------------------------------------------------------
__global__ __launch_bounds__(256) void v_transpose(
    const unsigned short* __restrict__ KV, unsigned short* __restrict__ Vt) {
  __shared__ unsigned short sh[32][33];
  const int s0 = blockIdx.x * 32, d0 = blockIdx.y * 32, bh = blockIdx.z;
  const int b = bh >> 4, h = bh & 15;
  const int tx = threadIdx.x & 31, ty = threadIdx.x >> 5;  // ty 0..7
#pragma unroll
  for (int i = 0; i < 32; i += 8)
    sh[ty + i][tx] = KV[((long)(b * 2048 + s0 + ty + i)) * 4096 + 2048 + h * 128 + d0 + tx];
  __syncthreads();
#pragma unroll
  for (int i = 0; i < 32; i += 8)
    Vt[((long)(bh * 128 + d0 + ty + i)) * 2048 + s0 + tx] = sh[tx][ty + i];
}

// ---------------------------------------------------------------------------
// block reduce (256 threads = 4 waves)
// ---------------------------------------------------------------------------
DEVI float blockReduceSum(float v) {
  v += __shfl_xor(v, 1);  v += __shfl_xor(v, 2);  v += __shfl_xor(v, 4);
  v += __shfl_xor(v, 8);  v += __shfl_xor(v, 16); v += __shfl_xor(v, 32);
  __shared__ float red[4];
  if ((threadIdx.x & 63) == 0) red[threadIdx.x >> 6] = v;
  __syncthreads();
  v = red[0] + red[1] + red[2] + red[3];
  __syncthreads();
  return v;
}

// ---------------------------------------------------------------------------
// LayerNorm over W cols, one block (256 thr) per row; input row stride ldin.
// f32 in -> bf16 out (out contiguous, stride W)
// ---------------------------------------------------------------------------
template <int W>
__global__ __launch_bounds__(256) void layernorm_bf16(
    const float* __restrict__ in, const float* __restrict__ g,
    const float* __restrict__ b, unsigned short* __restrict__ out, int ldin) {
  constexpr int VPT = W / 256;
  const long row = blockIdx.x;
  const float* x = in + row * ldin;
  float v[VPT];
  float s = 0.f;
#pragma unroll
  for (int i = 0; i < VPT; i++) { v[i] = x[threadIdx.x + i * 256]; s += v[i]; }
  s = blockReduceSum(s);
  const float mean = s * (1.0f / W);
  float s2 = 0.f;
#pragma unroll
  for (int i = 0; i < VPT; i++) { float d = v[i] - mean; s2 += d * d; }
  s2 = blockReduceSum(s2);
  const float rstd = rsqrtf(s2 * (1.0f / W) + 1e-5f);
#pragma unroll
  for (int i = 0; i < VPT; i++) {
    const int c = threadIdx.x + i * 256;
    out[row * W + c] = f2bf((v[i] - mean) * rstd * g[c] + b[c]);
  }
}

// ---------------------------------------------------------------------------
// combine_ln: fused W_o-combine + residual + LayerNorm (W=2048).
//   x2 = x + p0 + p1 ; h1 = LN(x2) * g + b
// ---------------------------------------------------------------------------
__global__ __launch_bounds__(256) void combine_ln(
    const unsigned short* __restrict__ p, const float* __restrict__ xres,
    const float* __restrict__ g, const float* __restrict__ b,
    float* __restrict__ x2, unsigned short* __restrict__ h1, long n) {
  const int c0 = threadIdx.x * 8;
  const long base = (long)blockIdx.x * 2048 + c0;
  float v[8];
  float s = 0.f;
#pragma unroll
  for (int hh = 0; hh < 2; hh++) {
    const long i = base + hh * 4;
    const ushort4 a  = *reinterpret_cast<const ushort4*>(p + i);
    const ushort4 bb = *reinterpret_cast<const ushort4*>(p + n + i);
    const float4 r = *reinterpret_cast<const float4*>(xres + i);
    float4 o;
    o.x = r.x + bf2f(a.x) + bf2f(bb.x);
    o.y = r.y + bf2f(a.y) + bf2f(bb.y);
    o.z = r.z + bf2f(a.z) + bf2f(bb.z);
    o.w = r.w + bf2f(a.w) + bf2f(bb.w);
    *reinterpret_cast<float4*>(x2 + i) = o;
    v[hh * 4 + 0] = o.x; v[hh * 4 + 1] = o.y;
    v[hh * 4 + 2] = o.z; v[hh * 4 + 3] = o.w;
    s += o.x + o.y + o.z + o.w;
  }
  s = blockReduceSum(s);
  const float mean = s * (1.0f / 2048.f);
  float s2 = 0.f;
#pragma unroll
  for (int i = 0; i < 8; i++) { float d = v[i] - mean; s2 += d * d; }
  s2 = blockReduceSum(s2);
  const float rstd = rsqrtf(s2 * (1.0f / 2048.f) + 1e-5f);
#pragma unroll
  for (int hh = 0; hh < 2; hh++) {
    const float4 gv = *reinterpret_cast<const float4*>(g + c0 + hh * 4);
    const float4 bv = *reinterpret_cast<const float4*>(b + c0 + hh * 4);
    ushort4 o;
    o.x = f2bf((v[hh * 4 + 0] - mean) * rstd * gv.x + bv.x);
    o.y = f2bf((v[hh * 4 + 1] - mean) * rstd * gv.y + bv.y);
    o.z = f2bf((v[hh * 4 + 2] - mean) * rstd * gv.z + bv.z);
    o.w = f2bf((v[hh * 4 + 3] - mean) * rstd * gv.w + bv.w);
    *reinterpret_cast<ushort4*>(h1 + base + hh * 4) = o;
  }
}

// ---------------------------------------------------------------------------
// gemm_bt: C(MxN) = A * Bt^T, 128x128 tile, BK=32, 4 waves (for small-N
// GEMMs: merged dq|dkv, Q-up).
// ---------------------------------------------------------------------------
template <bool BIAS, bool RELU, bool RES, bool OBF16>
__global__ __launch_bounds__(256) void gemm_bt(
    const unsigned short* __restrict__ A, const unsigned short* __restrict__ Bt,
    const float* __restrict__ bias, const float* __restrict__ res,
    void* __restrict__ Cout, int M, int N, int K) {
  __shared__ __align__(16) unsigned short As[2][128 * 32];
  __shared__ __align__(16) unsigned short Bs[2][128 * 32];

  const int m0 = blockIdx.x * 128;
  const int n0 = blockIdx.y * 128;
  const int tid = threadIdx.x;
  const int lane = tid & 63, w = tid >> 6;
  const int wr = (w >> 1) * 64, wc = (w & 1) * 64;
  const int lrow = lane & 15, lk = (lane >> 4) * 8;

  f32x4 acc[4][4] = {};

  const int nt = K >> 5;
  const int r_ = (tid * 8) >> 5;      // 0..63
  const int c_ = (tid * 8) & 31;

#define STAGE(buf, t)                                                        \
  {                                                                          \
    const long k0 = (long)(t) * 32;                                          \
    GLDS16(A + (long)(m0 + r_) * K + k0 + c_, &As[buf][tid * 8]);            \
    GLDS16(A + (long)(m0 + 64 + r_) * K + k0 + c_, &As[buf][2048 + tid * 8]);\
    GLDS16(Bt + (long)(n0 + r_) * K + k0 + c_, &Bs[buf][tid * 8]);           \
    GLDS16(Bt + (long)(n0 + 64 + r_) * K + k0 + c_, &Bs[buf][2048 + tid * 8]);\
  }

  STAGE(0, 0)
  __syncthreads();
  int cur = 0;
  for (int t = 0; t < nt; t++) {
    if (t + 1 < nt) STAGE(cur ^ 1, t + 1)
    bf16x8 fa[4], fb[4];
#pragma unroll
    for (int i = 0; i < 4; i++) {
      fa[i] = *reinterpret_cast<const bf16x8*>(&As[cur][(wr + i * 16 + lrow) * 32 + lk]);
      fb[i] = *reinterpret_cast<const bf16x8*>(&Bs[cur][(wc + i * 16 + lrow) * 32 + lk]);
    }
#pragma unroll
    for (int i = 0; i < 4; i++)
#pragma unroll
      for (int j = 0; j < 4; j++)
        acc[i][j] = __builtin_amdgcn_mfma_f32_16x16x32_bf16(fa[i], fb[j], acc[i][j], 0, 0, 0);
    __syncthreads();
    cur ^= 1;
  }
#undef STAGE

#pragma unroll
  for (int i = 0; i < 4; i++) {
#pragma unroll
    for (int j = 0; j < 4; j++) {
      const int row = m0 + wr + i * 16 + ((lane >> 4) << 2);
      const int col = n0 + wc + j * 16 + lrow;
      float bv = 0.f;
      if (BIAS) bv = bias[col];
#pragma unroll
      for (int r = 0; r < 4; r++) {
        float v = acc[i][j][r];
        const long idx = (long)(row + r) * N + col;
        if (BIAS) v += bv;
        if (RELU) v = fmaxf(v, 0.f);
        if (RES) v += res[idx];
        if (OBF16) ((unsigned short*)Cout)[idx] = f2bf(v);
        else       ((float*)Cout)[idx] = v;
      }
    }
  }
}

// ---------------------------------------------------------------------------
// gemm256p: 4-phase pipelined 256x256 GEMM, BK=64, 8 waves (512 thr).
// DS-BOUND ANALYSIS (R9): the R6 structure spends ~94% of tile time on the
// LDS read pipe (48 b128 reads/wave/tile x 8 waves x ~12cy = 4608cy vs 4880
// observed); MFMA needs only ~2484cy/SIMD. Fix: GRAY-CODE quadrant order
// (0,0)->(0,1)->(1,1)->(1,0) with operand-fragment REUSE across adjacent
// phases: P1 reads fa+fb (12), P2 reads fb only (4, fa reused), P3 reads fa
// only (8, fb reused), P4 reads fb only (4, fa reused) -> 28 reads/tile.
// Peak live frag regs unchanged vs R6 (fa 32 + fb 16) — no R8-style spill.
// Staging (2 glds per STG_*): P1:Ah0(t+1) P2:Bh1(t+1) P3:Bh0(t+1) P4:Ah1(t+1).
// Sync ledger (FIFO queue [Ah0',Bh1',Bh0',Ah1']):
//   end-P2: outstanding {Ah1(t),Ah0',Bh1'}=6 -> vmcnt(4) drains Ah1(t)
//           (needed by P3) + barrier.  [last tile: vmcnt(0)+barrier]
//   end-P4: outstanding 8 -> vmcnt(2) drains {Ah0',Bh1',Bh0'} (needed by
//           P1/P2 of t+1) + barrier; Ah1' stays in flight, drained by the
//           next tile's end-P2 wait.
// 2 barriers/tile; never drains to 0 mid-loop. WAR: reads target bu,
// stages target bn; the end-P4 barrier separates tile t-1 reads from
// tile t's writes into that buffer.
// Swizzle: 16B slot s of row r holds k-seg s ^ ((r>>1)&3) (measured 0 confl).
// blockIdx.z = split-K slice: A/Bt advanced by z*kOff, C by z*M*N.
// ---------------------------------------------------------------------------
template <bool BIAS, bool RELU, bool OBF16>
__global__ __launch_bounds__(512, 1) void gemm256p(
    const unsigned short* __restrict__ A, const unsigned short* __restrict__ Bt,
    const float* __restrict__ bias, void* __restrict__ Cout,
    int M, int N, int lda, int ldb, int kLen, long kOff) {
  __shared__ __align__(16) unsigned short L[2][2][2][256 * 32];

  const int m0 = blockIdx.x * 256, n0 = blockIdx.y * 256;
  const long ka = (long)blockIdx.z * kOff;
  const int tid = threadIdx.x;
  const int lane = tid & 63, w = tid >> 6;
  const int sr = (w >> 2) * 64, sc = (w & 3) * 32;
  const int g = lane >> 4, lrow = lane & 15;
  const int r_ = tid >> 2, s_ = tid & 3;

  f32x4 acc[2][2][4][2] = {};
  const int nt = kLen >> 6;

#define STG1(bb, ab, h, kh, t, P, base0, ld)                                   \
  {                                                                            \
    const long k0 = ka + (long)(t) * 64 + (kh) * 32;                           \
    const int rr = (h) * 128 + r_;                                             \
    GLDS16((P) + (long)((base0) + rr) * (ld) + k0 + ((s_ ^ ((rr >> 1) & 3)) << 3), \
           &L[bb][ab][kh][((h) * 512 + tid) * 8]);                             \
  }
#define STG_A(bb, h, t) STG1(bb, 0, h, 0, t, A, m0, lda) STG1(bb, 0, h, 1, t, A, m0, lda)
#define STG_B(bb, h, t) STG1(bb, 1, h, 0, t, Bt, n0, ldb) STG1(bb, 1, h, 1, t, Bt, n0, ldb)

#define RD_A(fa, bu, a)                                                        \
  _Pragma("unroll")                                                            \
  for (int kh = 0; kh < 2; kh++)                                               \
    _Pragma("unroll")                                                          \
    for (int i = 0; i < 4; i++) {                                              \
      const int rr = (a) * 128 + sr + i * 16 + lrow;                           \
      fa[kh][i] = *reinterpret_cast<const bf16x8*>(                            \
          &L[bu][0][kh][(rr * 4 + (g ^ ((rr >> 1) & 3))) * 8]);                \
    }
#define RD_B(fb, bu, b)                                                        \
  _Pragma("unroll")                                                            \
  for (int kh = 0; kh < 2; kh++)                                               \
    _Pragma("unroll")                                                          \
    for (int j = 0; j < 2; j++) {                                              \
      const int rr = (b) * 128 + sc + j * 16 + lrow;                           \
      fb[kh][j] = *reinterpret_cast<const bf16x8*>(                            \
          &L[bu][1][kh][(rr * 4 + (g ^ ((rr >> 1) & 3))) * 8]);                \
    }

#define PH_MFMA(a, b)                                                          \
  __builtin_amdgcn_s_setprio(1);                                               \
  _Pragma("unroll")                                                            \
  for (int kh = 0; kh < 2; kh++)                                               \
    _Pragma("unroll")                                                          \
    for (int i = 0; i < 4; i++)                                                \
      _Pragma("unroll")                                                        \
      for (int j = 0; j < 2; j++)                                              \
        acc[a][b][i][j] = __builtin_amdgcn_mfma_f32_16x16x32_bf16(             \
            fa[kh][i], fb[kh][j], acc[a][b][i][j], 0, 0, 0);                   \
  __builtin_amdgcn_s_setprio(0);

  // prologue: tile 0 -> buf 0, full drain (once per kernel)
  STG_A(0, 0, 0) STG_B(0, 0, 0) STG_B(0, 1, 0) STG_A(0, 1, 0)
  asm volatile("s_waitcnt vmcnt(0)\n\ts_barrier" ::: "memory");

  for (int t = 0; t < nt; t++) {
    const int bu = t & 1, bn = bu ^ 1;
    const bool pf = (t + 1 < nt);
    bf16x8 fa[2][4], fb[2][2];
    // P1 (0,0): fresh fa + fb; stage Ah0(t+1)
    RD_A(fa, bu, 0)
    RD_B(fb, bu, 0)
    if (pf) STG_A(bn, 0, t + 1)
    PH_MFMA(0, 0)
    // P2 (0,1): reuse fa, read Bh1; stage Bh1(t+1)
    RD_B(fb, bu, 1)
    if (pf) STG_B(bn, 1, t + 1)
    PH_MFMA(0, 1)
    if (pf) asm volatile("s_waitcnt vmcnt(4)\n\ts_barrier" ::: "memory");
    else    asm volatile("s_waitcnt vmcnt(0)\n\ts_barrier" ::: "memory");
    // P3 (1,1): reuse fb, read Ah1; stage Bh0(t+1)
    RD_A(fa, bu, 1)
    if (pf) STG_B(bn, 0, t + 1)
    PH_MFMA(1, 1)
    // P4 (1,0): reuse fa, read Bh0; stage Ah1(t+1)
    RD_B(fb, bu, 0)
    if (pf) STG_A(bn, 1, t + 1)
    PH_MFMA(1, 0)
    if (pf) asm volatile("s_waitcnt vmcnt(2)\n\ts_barrier" ::: "memory");
  }
#undef STG1
#undef STG_A
#undef STG_B
#undef RD_A
#undef RD_B
#undef PH_MFMA

  const long zoff = (long)blockIdx.z * (long)M * (long)N;
#pragma unroll
  for (int a = 0; a < 2; a++) {
#pragma unroll
    for (int b = 0; b < 2; b++) {
#pragma unroll
      for (int i = 0; i < 4; i++) {
#pragma unroll
        for (int j = 0; j < 2; j++) {
          const int row = m0 + a * 128 + sr + i * 16 + g * 4;
          const int col = n0 + b * 128 + sc + j * 16 + lrow;
          float bv = 0.f;
          if (BIAS) bv = bias[col];
#pragma unroll
          for (int r = 0; r < 4; r++) {
            float v = acc[a][b][i][j][r];
            if (BIAS) v += bv;
            if (RELU) v = fmaxf(v, 0.f);
            const long idx = zoff + (long)(row + r) * N + col;
            if (OBF16) ((unsigned short*)Cout)[idx] = f2bf(v);
            else       ((float*)Cout)[idx] = v;
          }
        }
      }
    }
  }
}

// ---------------------------------------------------------------------------
// combine split-K partials: out = p0 + p1 [+ bias[col]] + res  (f32)
// N = 2048 fixed (bias index = i & 2047), n = M*N, 4 elements/thread
// ---------------------------------------------------------------------------
template <bool BIAS>
__global__ __launch_bounds__(256) void combine2(
    const unsigned short* __restrict__ p, const float* __restrict__ bias,
    const float* __restrict__ res, float* __restrict__ out, long n) {
  const long i = ((long)blockIdx.x * 256 + threadIdx.x) * 4;
  if (i >= n) return;
  const ushort4 a = *reinterpret_cast<const ushort4*>(p + i);
  const ushort4 b = *reinterpret_cast<const ushort4*>(p + n + i);
  const float4 r = *reinterpret_cast<const float4*>(res + i);
  float4 o;
  o.x = bf2f(a.x) + bf2f(b.x) + r.x;
  o.y = bf2f(a.y) + bf2f(b.y) + r.y;
  o.z = bf2f(a.z) + bf2f(b.z) + r.z;
  o.w = bf2f(a.w) + bf2f(b.w) + r.w;
  if (BIAS) {
    const int col = (int)(i & 2047);
    const float4 bv = *reinterpret_cast<const float4*>(bias + col);
    o.x += bv.x; o.y += bv.y; o.z += bv.z; o.w += bv.w;
  }
  *reinterpret_cast<float4*>(out + i) = o;
}

// ---------------------------------------------------------------------------
// Causal flash attention, KVBLK=64, global_load_lds + XOR-swizzled tiles.
// ---------------------------------------------------------------------------
__global__ __launch_bounds__(256) void flash_attn(
    const unsigned short* __restrict__ Q, const unsigned short* __restrict__ KV,
    const unsigned short* __restrict__ Vt, unsigned short* __restrict__ O) {
  constexpr int S = 2048;
  const int tid = threadIdx.x, lane = tid & 63, w = tid >> 6;
  const int g = lane >> 4, lcol = lane & 15;
  const int wg = blockIdx.x;              // 0..511
  const int x8 = wg & 7, q64 = wg >> 3;   // q64 0..63
  const int p = q64 & 15, hi = q64 >> 4;
  const int bh = x8 * 4 + hi;             // 0..31
  const int b = bh >> 4, h = bh & 15;
  const long kvrow0 = (long)b * S;
  const int hd0 = h * 128;

  __shared__ __align__(16) unsigned short Kl[64 * 128];   // [k][d] swizzled
  __shared__ __align__(16) unsigned short Vl[128 * 64];   // [d][k] swizzled
  __shared__ __align__(16) unsigned short Pl[4 * 16 * 72];

  const float kscale = 0.08838834764831845f * 1.4426950408889634f; // /sqrt(128)*log2e

  for (int ti = 0; ti < 2; ti++) {
    const int t = ti ? (31 - p) : p;
    const int qbase = t * 64;
    bf16x8 qf[4];
#pragma unroll
    for (int dc = 0; dc < 4; dc++)
      qf[dc] = *reinterpret_cast<const bf16x8*>(
          Q + (kvrow0 + qbase + w * 16 + lcol) * 2048 + hd0 + dc * 32 + g * 8);
    f32x4 oacc[8] = {};
    float mst[4] = {NEG_INF, NEG_INF, NEG_INF, NEG_INF};
    float lst[4] = {0.f, 0.f, 0.f, 0.f};
    const int nk = t + 1;
    for (int kt = 0; kt < nk; kt++) {
      const int kv0 = kt * 64;
      __syncthreads();
#pragma unroll
      for (int i = 0; i < 4; i++) {
        const int o16 = i * 256 + tid;
        const int kr = o16 >> 4, ks = o16 & 15;
        GLDS16(KV + (kvrow0 + kv0 + kr) * 4096 + hd0 + 8 * (ks ^ (kr & 7)),
               Kl + o16 * 8);
        const int vd = o16 >> 3, vs = o16 & 7;
        GLDS16(Vt + ((long)bh * 128 + vd) * 2048 + kv0 + 8 * (vs ^ (vd & 7)),
               Vl + o16 * 8);
      }
      __syncthreads();
      // QK^T: 16q x 64k
      f32x4 sc[4] = {};
      __builtin_amdgcn_s_setprio(1);
#pragma unroll
      for (int dc = 0; dc < 4; dc++) {
#pragma unroll
        for (int c = 0; c < 4; c++) {
          const bf16x8 kf = *reinterpret_cast<const bf16x8*>(
              Kl + (c * 16 + lcol) * 128 + 8 * ((4 * dc + g) ^ (lcol & 7)));
          sc[c] = __builtin_amdgcn_mfma_f32_16x16x32_bf16(qf[dc], kf, sc[c], 0, 0, 0);
        }
      }
      __builtin_amdgcn_s_setprio(0);
      float s[4][4];
      const int qrow = qbase + w * 16 + g * 4;
      if (kt == nk - 1) {
#pragma unroll
        for (int c = 0; c < 4; c++) {
          const int col = kv0 + c * 16 + lcol;
#pragma unroll
          for (int r = 0; r < 4; r++)
            s[c][r] = (col <= qrow + r) ? sc[c][r] * kscale : NEG_INF;
        }
      } else {
#pragma unroll
        for (int c = 0; c < 4; c++)
#pragma unroll
          for (int r = 0; r < 4; r++) s[c][r] = sc[c][r] * kscale;
      }
      float pm[4];
#pragma unroll
      for (int r = 0; r < 4; r++) {
        float mx = fmaxf(fmaxf(s[0][r], s[1][r]), fmaxf(s[2][r], s[3][r]));
        mx = fmaxf(mx, __shfl_xor(mx, 1));
        mx = fmaxf(mx, __shfl_xor(mx, 2));
        mx = fmaxf(mx, __shfl_xor(mx, 4));
        mx = fmaxf(mx, __shfl_xor(mx, 8));
        pm[r] = mx;
      }
      bool need = false;
#pragma unroll
      for (int r = 0; r < 4; r++) need = need || (pm[r] > mst[r] + 11.5f);
      if (__any(need)) {
#pragma unroll
        for (int r = 0; r < 4; r++) {
          const float mnew = fmaxf(mst[r], pm[r]);
          const float corr = exp2f(mst[r] - mnew);
          mst[r] = mnew;
          lst[r] *= corr;
#pragma unroll
          for (int db = 0; db < 8; db++) oacc[db][r] *= corr;
        }
      }
#pragma unroll
      for (int r = 0; r < 4; r++) {
        float ps = 0.f;
#pragma unroll
        for (int c = 0; c < 4; c++) {
          const float pv = exp2f(s[c][r] - mst[r]);
          Pl[(w * 16 + g * 4 + r) * 72 + c * 16 + lcol] = f2bf(pv);
          ps += pv;
        }
        ps += __shfl_xor(ps, 1); ps += __shfl_xor(ps, 2);
        ps += __shfl_xor(ps, 4); ps += __shfl_xor(ps, 8);
        lst[r] += ps;
      }
      __builtin_amdgcn_s_setprio(1);
#pragma unroll
      for (int kk = 0; kk < 2; kk++) {
        const bf16x8 pf = *reinterpret_cast<const bf16x8*>(
            Pl + (w * 16 + lcol) * 72 + kk * 32 + g * 8);
#pragma unroll
        for (int db = 0; db < 8; db++) {
          const bf16x8 vf = *reinterpret_cast<const bf16x8*>(
              Vl + (db * 16 + lcol) * 64 + 8 * ((4 * kk + g) ^ (lcol & 7)));
          oacc[db] = __builtin_amdgcn_mfma_f32_16x16x32_bf16(pf, vf, oacc[db], 0, 0, 0);
        }
      }
      __builtin_amdgcn_s_setprio(0);
    }
#pragma unroll
    for (int db = 0; db < 8; db++)
#pragma unroll
      for (int r = 0; r < 4; r++) {
        const int qi = qbase + w * 16 + g * 4 + r;
        O[(kvrow0 + qi) * 2048 + hd0 + db * 16 + lcol] = f2bf(oacc[db][r] / lst[r]);
      }
  }
}

// ---------------------------------------------------------------------------
// launch
// ---------------------------------------------------------------------------
extern "C" void kernel_launch(void* const* d_in, const int* in_sizes, int n_in,
                              void* d_out, int out_size, void* d_ws, size_t ws_size,
                              hipStream_t stream) {
  (void)in_sizes; (void)n_in; (void)out_size; (void)ws_size;
  const float* x     = (const float*)d_in[0];
  const float* W_dq  = (const float*)d_in[1];
  const float* W_uq  = (const float*)d_in[2];
  const float* qlng  = (const float*)d_in[3];
  const float* qlnb  = (const float*)d_in[4];
  const float* W_dkv = (const float*)d_in[5];
  const float* W_ukv = (const float*)d_in[6];
  const float* klng  = (const float*)d_in[7];
  const float* klnb  = (const float*)d_in[8];
  const float* W_o   = (const float*)d_in[9];
  const float* n1g   = (const float*)d_in[10];
  const float* n1b   = (const float*)d_in[11];
  const float* n2g   = (const float*)d_in[12];
  const float* n2b   = (const float*)d_in[13];
  const float* fc1w  = (const float*)d_in[14];
  const float* fc1b  = (const float*)d_in[15];
  const float* fc2w  = (const float*)d_in[16];
  const float* fc2b  = (const float*)d_in[17];
  float* out = (float*)d_out;

  char* ws = (char*)d_ws;
  // region A [0,32M): normed -> Obuf -> fc2bb
  unsigned short* normed = (unsigned short*)(ws + 0);
  unsigned short* Obuf   = (unsigned short*)(ws + 0);
  unsigned short* fc2bb  = (unsigned short*)(ws + 0);
  // region B [32M,64M): cqkv_pre -> KV -> fc1bb -> fc2part
  float*          cqkv_pre = (float*)(ws + 33554432);
  unsigned short* KV       = (unsigned short*)(ws + 33554432);
  unsigned short* fc1bb    = (unsigned short*)(ws + 33554432);
  unsigned short* fc2part  = (unsigned short*)(ws + 33554432);
  // region C [64M,68M): cq
  unsigned short* cq  = (unsigned short*)(ws + 67108864);
  // region D [68M,84.7M): Qb -> h1
  unsigned short* Qb = (unsigned short*)(ws + 71303168);
  unsigned short* h1 = (unsigned short*)(ws + 71303168);
  // region E [84M,117.6M): ckv (early) -> x2 (late)
  unsigned short* ckv = (unsigned short*)(ws + 88080384);
  float* x2           = (float*)(ws + 88080384);
  // region F [116M,180M): Vt -> wopart -> hmid
  unsigned short* Vtb    = (unsigned short*)(ws + 121634816);
  unsigned short* wopart = (unsigned short*)(ws + 121634816);
  unsigned short* hmid   = (unsigned short*)(ws + 121634816);
  // region G [180M,...): transposed/cast weights
  unsigned short* dqkv_t = (unsigned short*)(ws + 188743680);  // 1024 x 2048
  unsigned short* uq_t   = dqkv_t + 2097152;                   // 2048 x 512
  unsigned short* ukv_t  = uq_t + 1048576;                     // 4096 x 512
  unsigned short* wo_b   = ukv_t + 2097152;                    // 2048 x 2048

  const dim3 blk(256);
  const dim3 blk8(512);

  transpose_cast<<<dim3(512 / 32, 2048 / 32), blk, 0, stream>>>(W_dq, dqkv_t, 2048, 512);
  transpose_cast<<<dim3(512 / 32, 2048 / 32), blk, 0, stream>>>(W_dkv, dqkv_t + 512 * 2048, 2048, 512);
  transpose_cast<<<dim3(2048 / 32, 512 / 32), blk, 0, stream>>>(W_uq, uq_t, 512, 2048);
  transpose_cast<<<dim3(4096 / 32, 512 / 32), blk, 0, stream>>>(W_ukv, ukv_t, 512, 4096);
  cast_f32_bf16<<<2048 * 2048 / 1024, blk, 0, stream>>>(W_o, wo_b, 2048 * 2048);

  // LN1
  layernorm_bf16<2048><<<4096, blk, 0, stream>>>(x, n1g, n1b, normed, 2048);
  // cqkv_pre = normed @ [W_dq | W_dkv]
  gemm_bt<false, false, false, false><<<dim3(32, 8), blk, 0, stream>>>(
      normed, dqkv_t, nullptr, nullptr, cqkv_pre, 4096, 1024, 2048);
  layernorm_bf16<512><<<4096, blk, 0, stream>>>(cqkv_pre, qlng, qlnb, cq, 1024);
  layernorm_bf16<512><<<4096, blk, 0, stream>>>(cqkv_pre + 512, klng, klnb, ckv, 1024);
  // Q = cq @ W_uq
  gemm_bt<false, false, false, true><<<dim3(32, 16), blk, 0, stream>>>(
      cq, uq_t, nullptr, nullptr, Qb, 4096, 2048, 512);
  // KV = ckv @ W_ukv
  gemm256p<false, false, true><<<dim3(16, 16), blk8, 0, stream>>>(
      ckv, ukv_t, nullptr, KV, 4096, 4096, 512, 512, 512, 0);
  // V transpose for conflict-free PV fragments
  v_transpose<<<dim3(64, 4, 32), blk, 0, stream>>>(KV, Vtb);
  // attention
  flash_attn<<<dim3(512), blk, 0, stream>>>(Qb, KV, Vtb, Obuf);
  // fc1 weights cast (region B free after attention)
  cast_f32_bf16<<<8192 * 2048 / 1024, blk, 0, stream>>>(fc1w, fc1bb, 8192L * 2048);
  // W_o partials: split-K=2 (Vt dead -> region F)
  gemm256p<false, false, true><<<dim3(16, 8, 2), blk8, 0, stream>>>(
      Obuf, wo_b, nullptr, wopart, 4096, 2048, 2048, 2048, 1024, 1024);
  // fc2 weights cast (region A free after W_o gemm)
  cast_f32_bf16<<<2048 * 8192 / 1024, blk, 0, stream>>>(fc2w, fc2bb, 2048L * 8192);
  // x2 = x + p0 + p1 ; h1 = LN(x2)   (fused)
  combine_ln<<<4096, blk, 0, stream>>>(wopart, x, n2g, n2b, x2, h1, 8388608L);
  // h_mid = relu(h1 @ fc1^T + b1)
  gemm256p<true, true, true><<<dim3(16, 32), blk8, 0, stream>>>(
      h1, fc1bb, fc1b, hmid, 4096, 8192, 2048, 2048, 2048, 0);
  // fc2 partials: split-K=2
  gemm256p<false, false, true><<<dim3(16, 8, 2), blk8, 0, stream>>>(
      hmid, fc2bb, nullptr, fc2part, 4096, 2048, 8192, 8192, 4096, 4096);
  // out = p0 + p1 + b2 + x2
  combine2<true><<<8192, blk, 0, stream>>>(fc2part, fc2b, x2, out, 8388608L);
}